// Round 1
// baseline (817.055 us; speedup 1.0000x reference)
//
#include <hip/hip_runtime.h>
#include <stdint.h>

typedef _Float16 f16;
typedef _Float16 half8 __attribute__((ext_vector_type(8)));
typedef _Float16 half4v __attribute__((ext_vector_type(4)));
typedef float f32x4 __attribute__((ext_vector_type(4)));

#define DEV static __device__ __forceinline__

DEV f32x4 mfma16(half8 a, half8 b, f32x4 c) {
  return __builtin_amdgcn_mfma_f32_16x16x32_f16(a, b, c, 0, 0, 0);
}

// Problem constants: B=2, S=2048, DIM=1024, H=16, D=64, B1=B2=8, F=32, ITERS=2
// seq position s = g*64 + i*8 + j ; kv position = f*64 + k*8 + l

// ---------------- K1: cast x, wq|wk|wv -> fp16 ----------------
__global__ __launch_bounds__(256) void k_cast(
    const float* __restrict__ x, const float* __restrict__ wq,
    const float* __restrict__ wk, const float* __restrict__ wv,
    f16* __restrict__ xh, f16* __restrict__ wcat) {
  const int64_t nx4 = 4194304 / 4;   // x elems /4
  const int64_t nw4 = 1048576 / 4;   // each w /4
  int64_t stride = (int64_t)gridDim.x * blockDim.x;
  for (int64_t i = (int64_t)blockIdx.x * blockDim.x + threadIdx.x;
       i < nx4 + 3 * nw4; i += stride) {
    const float* src; f16* dst; int64_t off;
    if (i < nx4) { src = x; dst = xh; off = i; }
    else {
      int64_t r = i - nx4;
      int ws_ = (int)(r / nw4);
      off = r - (int64_t)ws_ * nw4;
      src = (ws_ == 0) ? wq : ((ws_ == 1) ? wk : wv);
      dst = wcat + (int64_t)ws_ * 1048576;
    }
    float4 v = ((const float4*)src)[off];
    half4v hh; hh[0] = (f16)v.x; hh[1] = (f16)v.y; hh[2] = (f16)v.z; hh[3] = (f16)v.w;
    ((half4v*)dst)[off] = hh;
  }
}

// ---------------- K2: P[4096][3072] = xh[4096][1024] @ wcat[3072][1024]^T ----
// 128x128 tile, 256 thr (4 waves, each 64x64 quadrant), BK=64, fp16 MFMA.
__global__ __launch_bounds__(256) void k_gemm(
    const f16* __restrict__ A, const f16* __restrict__ Bm,
    float* __restrict__ P) {
  __shared__ f16 As[128 * 72];   // +8 pad: conflict-free b128 frag reads
  __shared__ f16 Bs[128 * 72];
  const int t = threadIdx.x;
  const int wave = t >> 6, lane = t & 63, quad = lane >> 4, ln = lane & 15;
  const int tM = blockIdx.x / 24, tN = blockIdx.x % 24;
  const int wm = wave >> 1, wn = wave & 1;
  f32x4 acc[4][4];
#pragma unroll
  for (int a = 0; a < 4; ++a)
#pragma unroll
    for (int b = 0; b < 4; ++b) { f32x4 z = {0.f, 0.f, 0.f, 0.f}; acc[a][b] = z; }
  const int r = t >> 1, hf = t & 1;
  const f16* Ag = A + (int64_t)(tM * 128 + r) * 1024 + hf * 32;
  const f16* Bg = Bm + (int64_t)(tN * 128 + r) * 1024 + hf * 32;
  f16* Asw = &As[r * 72 + hf * 32];
  f16* Bsw = &Bs[r * 72 + hf * 32];
  for (int kt = 0; kt < 16; ++kt) {
    half8 a0 = *(const half8*)(Ag + kt * 64);
    half8 a1 = *(const half8*)(Ag + kt * 64 + 8);
    half8 a2 = *(const half8*)(Ag + kt * 64 + 16);
    half8 a3 = *(const half8*)(Ag + kt * 64 + 24);
    half8 b0 = *(const half8*)(Bg + kt * 64);
    half8 b1 = *(const half8*)(Bg + kt * 64 + 8);
    half8 b2 = *(const half8*)(Bg + kt * 64 + 16);
    half8 b3 = *(const half8*)(Bg + kt * 64 + 24);
    __syncthreads();   // previous compute done before LDS overwrite
    *(half8*)(Asw) = a0; *(half8*)(Asw + 8) = a1;
    *(half8*)(Asw + 16) = a2; *(half8*)(Asw + 24) = a3;
    *(half8*)(Bsw) = b0; *(half8*)(Bsw + 8) = b1;
    *(half8*)(Bsw + 16) = b2; *(half8*)(Bsw + 24) = b3;
    __syncthreads();
#pragma unroll
    for (int ks = 0; ks < 2; ++ks) {
      half8 bf[4];
#pragma unroll
      for (int tn = 0; tn < 4; ++tn)
        bf[tn] = *(const half8*)&Bs[(wn * 64 + tn * 16 + ln) * 72 + ks * 32 + quad * 8];
#pragma unroll
      for (int tm = 0; tm < 4; ++tm) {
        half8 af = *(const half8*)&As[(wm * 64 + tm * 16 + ln) * 72 + ks * 32 + quad * 8];
#pragma unroll
        for (int tn = 0; tn < 4; ++tn)
          acc[tm][tn] = mfma16(af, bf[tn], acc[tm][tn]);
      }
    }
  }
#pragma unroll
  for (int tm = 0; tm < 4; ++tm)
#pragma unroll
    for (int tn = 0; tn < 4; ++tn)
#pragma unroll
      for (int r2 = 0; r2 < 4; ++r2) {
        int row = tM * 128 + wm * 64 + tm * 16 + quad * 4 + r2;
        int col = tN * 128 + wn * 64 + tn * 16 + ln;
        P[(int64_t)row * 3072 + col] = acc[tm][tn][r2];
      }
}

// ---------------- K3: rmsnorm+rope+scale for q,k; v -> transposed fp16 ------
// qh,kh: [b][h][s][d] fp16 ; vth: [b][h][d][s] fp16 (transposed once here,
// so attention B-fragments are contiguous 16B LDS reads).
__global__ __launch_bounds__(256) void k_epilogue(
    const float* __restrict__ P, const float* __restrict__ cosg,
    const float* __restrict__ sing, const float* __restrict__ gq,
    const float* __restrict__ gk, f16* __restrict__ qh,
    f16* __restrict__ kh, f16* __restrict__ vth) {
  __shared__ f16 vbuf[64 * 72];
  const int t = threadIdx.x;
  const int bid = blockIdx.x;
  const int st = bid & 31, h = (bid >> 5) & 15, b = bid >> 9;
  const int r = t >> 2, qt = t & 3, c0 = qt * 16;
  const int s = st * 64 + r;
  const int64_t rowbase = (int64_t)(b * 2048 + s) * 3072;
  const float scale = 0.35355339059327373f;  // 64^-0.25
#pragma unroll
  for (int m = 0; m < 2; ++m) {
    const float* gv = (m == 0) ? gq : gk;
    const int colbase = m * 1024 + h * 64 + c0;
    float xv[16];
#pragma unroll
    for (int c = 0; c < 4; ++c) {
      float4 v4 = *(const float4*)&P[rowbase + colbase + c * 4];
      xv[c * 4 + 0] = v4.x; xv[c * 4 + 1] = v4.y;
      xv[c * 4 + 2] = v4.z; xv[c * 4 + 3] = v4.w;
    }
    float ss = 0.f;
#pragma unroll
    for (int c = 0; c < 16; ++c) ss += xv[c] * xv[c];
    ss += __shfl_xor(ss, 1, 64);
    ss += __shfl_xor(ss, 2, 64);
    float rs = rsqrtf(ss * (1.f / 64.f) + 1e-6f);
    alignas(16) f16 res[16];
#pragma unroll
    for (int ci = 0; ci < 16; ci += 2) {
      int d0 = c0 + ci, d1 = d0 + 1;
      float av = xv[ci] * rs * gv[d0];
      float bv = xv[ci + 1] * rs * gv[d1];
      float c0v = cosg[s * 64 + d0], c1v = cosg[s * 64 + d1];
      float s0v = sing[s * 64 + d0], s1v = sing[s * 64 + d1];
      res[ci]     = (f16)((av * c0v - bv * s0v) * scale);
      res[ci + 1] = (f16)((bv * c1v + av * s1v) * scale);
    }
    f16* dst = ((m == 0) ? qh : kh) + (int64_t)((b * 16 + h) * 2048 + s) * 64 + c0;
    *(half8*)dst = *(const half8*)&res[0];
    *(half8*)(dst + 8) = *(const half8*)&res[8];
  }
  {
    const int colbase = 2048 + h * 64 + c0;
#pragma unroll
    for (int c = 0; c < 4; ++c) {
      float4 v4 = *(const float4*)&P[rowbase + colbase + c * 4];
      vbuf[(c0 + c * 4 + 0) * 72 + r] = (f16)v4.x;
      vbuf[(c0 + c * 4 + 1) * 72 + r] = (f16)v4.y;
      vbuf[(c0 + c * 4 + 2) * 72 + r] = (f16)v4.z;
      vbuf[(c0 + c * 4 + 3) * 72 + r] = (f16)v4.w;
    }
    __syncthreads();
    const int d = t >> 2, sc = qt * 16;
    alignas(16) f16 tmp[16];
#pragma unroll
    for (int ci = 0; ci < 16; ++ci) tmp[ci] = vbuf[d * 72 + sc + ci];
    f16* dst = vth + (int64_t)((b * 16 + h) * 64 + d) * 2048 + st * 64 + sc;
    *(half8*)dst = *(const half8*)&tmp[0];
    *(half8*)(dst + 8) = *(const half8*)&tmp[8];
  }
}

// ---------------- K4: monarch attention per (b,h,g) -------------------------
__global__ __launch_bounds__(256) void k_attn(
    const f16* __restrict__ qh, const f16* __restrict__ kh,
    const f16* __restrict__ vth, float* __restrict__ out) {
  __shared__ f16 qs[64 * 72];        // 9216 B
  __shared__ f16 kvs[64 * 72];       // 9216 B (k, then reused for v)
  __shared__ float Ssh[64 * 65];     // 16640 B  scores S_f
  __shared__ float LBsh[32 * 512];   // 65536 B  L / bL logits [f][j][k][i]
  __shared__ f16 Rsh[32 * 512];      // 32768 B  R [f][k][j][l]
  __shared__ float cLb[64];          // [j][k]  sum_l R log R

  const int t = threadIdx.x;
  const int wave = t >> 6, lane = t & 63, quad = lane >> 4, ln = lane & 15;
  const int gid = blockIdx.x;
  const int g = 31 - (gid & 31);     // large g first for load balance
  const int bh = gid >> 5;

  const f16* qg = qh + (int64_t)(bh * 2048 + g * 64) * 64;
  const f16* kb = kh + (int64_t)bh * 2048 * 64;
  const f16* vb = vth + (int64_t)bh * 64 * 2048;

  {
    const int r = t >> 2, c0 = (t & 3) * 16;
    *(half8*)&qs[r * 72 + c0] = *(const half8*)&qg[r * 64 + c0];
    *(half8*)&qs[r * 72 + c0 + 8] = *(const half8*)&qg[r * 64 + c0 + 8];
  }

  for (int iter = 0; iter < 2; ++iter) {
    for (int f = 0; f <= g; ++f) {
      __syncthreads();
      { // stage k_f
        const int r = t >> 2, c0 = (t & 3) * 16;
        const f16* src = kb + (int64_t)f * 64 * 64;
        *(half8*)&kvs[r * 72 + c0] = *(const half8*)&src[r * 64 + c0];
        *(half8*)&kvs[r * 72 + c0 + 8] = *(const half8*)&src[r * 64 + c0 + 8];
      }
      __syncthreads();
      { // S = q_g k_f^T : wave computes column strip tn=wave
        f32x4 acc[4];
#pragma unroll
        for (int tm = 0; tm < 4; ++tm) { f32x4 z = {0.f, 0.f, 0.f, 0.f}; acc[tm] = z; }
#pragma unroll
        for (int ks = 0; ks < 2; ++ks) {
          half8 b8 = *(const half8*)&kvs[(wave * 16 + ln) * 72 + ks * 32 + quad * 8];
#pragma unroll
          for (int tm = 0; tm < 4; ++tm) {
            half8 a8 = *(const half8*)&qs[(tm * 16 + ln) * 72 + ks * 32 + quad * 8];
            acc[tm] = mfma16(a8, b8, acc[tm]);
          }
        }
#pragma unroll
        for (int tm = 0; tm < 4; ++tm)
#pragma unroll
          for (int r2 = 0; r2 < 4; ++r2)
            Ssh[(tm * 16 + quad * 4 + r2) * 65 + wave * 16 + ln] = acc[tm][r2];
      }
      __syncthreads();
      { // R-step: bR,cR -> softmax over l -> Rsh, cLb
        float va[2];
#pragma unroll
        for (int e = 0; e < 2; ++e) {
          const int o = t + e * 256;
          const int k_ = o >> 6, j = (o >> 3) & 7, l = o & 7;
          float bR, cR;
          if (iter == 0) {  // L = block-identity: bR = S[(k,j),(k,l)], cR = 1
            bR = Ssh[(k_ * 8 + j) * 65 + k_ * 8 + l];
            cR = 1.f;
          } else {
            bR = 0.f; cR = 0.f;
            const float* Lrow = &LBsh[f * 512 + j * 64 + k_ * 8];
            const float* Sp = &Ssh[j * 65 + k_ * 8 + l];
#pragma unroll
            for (int i = 0; i < 8; ++i) {
              float Lv = Lrow[i];
              cR += Lv;
              bR += Lv * Sp[i * 520];  // S[(i*8+j)][k*8+l], row stride 65
            }
          }
          va[e] = bR / (cR + 1e-6f);
        }
#pragma unroll
        for (int e = 0; e < 2; ++e) {
          const int o = t + e * 256;
          const int k_ = o >> 6, j = (o >> 3) & 7, l = o & 7;
          float m = va[e];
          m = fmaxf(m, __shfl_xor(m, 1, 64));
          m = fmaxf(m, __shfl_xor(m, 2, 64));
          m = fmaxf(m, __shfl_xor(m, 4, 64));
          float ex = __expf(va[e] - m);
          float sm = ex;
          sm += __shfl_xor(sm, 1, 64);
          sm += __shfl_xor(sm, 2, 64);
          sm += __shfl_xor(sm, 4, 64);
          float rr = ex / sm;
          Rsh[f * 512 + o] = (f16)rr;
          float rl = rr * __logf(fmaxf(rr, 1e-30f));
          rl += __shfl_xor(rl, 1, 64);
          rl += __shfl_xor(rl, 2, 64);
          rl += __shfl_xor(rl, 4, 64);
          if (l == 0) cLb[j * 8 + k_] = rl;
        }
      }
      __syncthreads();
      { // bL-step: M[f,j,k,i] = sum_l R*S - cL  (overwrites L[f] in place)
#pragma unroll
        for (int e = 0; e < 2; ++e) {
          const int o = t + e * 256;
          const int j = o >> 6, k_ = (o >> 3) & 7, i = o & 7;
          const f16* Rr = &Rsh[f * 512 + k_ * 64 + j * 8];
          const float* Sp = &Ssh[(i * 8 + j) * 65 + k_ * 8];
          float bL = 0.f;
#pragma unroll
          for (int l = 0; l < 8; ++l) bL += (float)Rr[l] * Sp[l];
          LBsh[f * 512 + o] = bL - cLb[j * 8 + k_];
        }
      }
    }
    __syncthreads();
    { // joint softmax over (f<=g, k) per (j,i): LB logits -> new L
      const int p = t >> 2, sub = t & 3;
      const int j = p >> 3, i = p & 7;
      const int base = j * 64 + i;
      float mx = -1e30f;
      for (int f = sub; f <= g; f += 4)
#pragma unroll
        for (int k_ = 0; k_ < 8; ++k_)
          mx = fmaxf(mx, LBsh[f * 512 + base + k_ * 8]);
      mx = fmaxf(mx, __shfl_xor(mx, 1, 64));
      mx = fmaxf(mx, __shfl_xor(mx, 2, 64));
      float se = 0.f;
      for (int f = sub; f <= g; f += 4)
#pragma unroll
        for (int k_ = 0; k_ < 8; ++k_)
          se += __expf(LBsh[f * 512 + base + k_ * 8] - mx);
      se += __shfl_xor(se, 1, 64);
      se += __shfl_xor(se, 2, 64);
      const float inv = 1.f / se;
      for (int f = sub; f <= g; f += 4)
#pragma unroll
        for (int k_ = 0; k_ < 8; ++k_) {
          const int idx = f * 512 + base + k_ * 8;
          LBsh[idx] = __expf(LBsh[idx] - mx) * inv;
        }
    }
  }
  // output pass: out[(i,j),d] = sum_f W_f @ v_f ; W[(i,j),(k,l)] = L*R
  f32x4 oacc[4];
#pragma unroll
  for (int tm = 0; tm < 4; ++tm) { f32x4 z = {0.f, 0.f, 0.f, 0.f}; oacc[tm] = z; }
  for (int f = 0; f <= g; ++f) {
    __syncthreads();
    { // stage v_f (already [d][s] in global, so rows are contiguous)
      const int r = t >> 2, c0 = (t & 3) * 16;
      const f16* src = vb + f * 64;
      *(half8*)&kvs[r * 72 + c0] = *(const half8*)&src[(int64_t)r * 2048 + c0];
      *(half8*)&kvs[r * 72 + c0 + 8] = *(const half8*)&src[(int64_t)r * 2048 + c0 + 8];
    }
    __syncthreads();
#pragma unroll
    for (int ks = 0; ks < 2; ++ks) {
      half8 v8 = *(const half8*)&kvs[(wave * 16 + ln) * 72 + ks * 32 + quad * 8];
      const int k4 = ks * 4 + quad;
#pragma unroll
      for (int tm = 0; tm < 4; ++tm) {
        const int m = tm * 16 + ln;
        const int i = m >> 3, j = m & 7;
        const float Lval = LBsh[f * 512 + j * 64 + k4 * 8 + i];
        half8 r8 = *(const half8*)&Rsh[f * 512 + k4 * 64 + j * 8];
        const f16 Lh = (f16)Lval;
        half8 w8;
#pragma unroll
        for (int l = 0; l < 8; ++l) w8[l] = r8[l] * Lh;
        oacc[tm] = mfma16(w8, v8, oacc[tm]);
      }
    }
  }
  float* ob = out + (int64_t)((bh >> 4) * 2048 + g * 64) * 1024 + (bh & 15) * 64;
#pragma unroll
  for (int tm = 0; tm < 4; ++tm)
#pragma unroll
    for (int r2 = 0; r2 < 4; ++r2)
      ob[(int64_t)(tm * 16 + quad * 4 + r2) * 1024 + wave * 16 + ln] = oacc[tm][r2];
}

// ---------------------------------------------------------------------------
extern "C" void kernel_launch(void* const* d_in, const int* in_sizes, int n_in,
                              void* d_out, int out_size, void* d_ws, size_t ws_size,
                              hipStream_t stream) {
  const float* x    = (const float*)d_in[0];
  const float* cosg = (const float*)d_in[1];
  const float* sing = (const float*)d_in[2];
  const float* wq   = (const float*)d_in[3];
  const float* wk   = (const float*)d_in[4];
  const float* wv   = (const float*)d_in[5];
  const float* gq   = (const float*)d_in[6];
  const float* gk   = (const float*)d_in[7];
  float* out = (float*)d_out;

  char* ws = (char*)d_ws;
  f16*   xh   = (f16*)(ws);                       // 8,388,608 B
  f16*   wcat = (f16*)(ws + 8388608);             // 6,291,456 B
  float* P    = (float*)(ws + 14680064);          // 50,331,648 B
  f16*   qh   = (f16*)(ws + 65011712);            // 8,388,608 B
  f16*   kh   = (f16*)(ws + 73400320);            // 8,388,608 B
  f16*   vth  = (f16*)(ws + 81788928);            // 8,388,608 B -> total ~86 MB

  hipLaunchKernelGGL(k_cast, dim3(1024), dim3(256), 0, stream, x, wq, wk, wv, xh, wcat);
  hipLaunchKernelGGL(k_gemm, dim3(768), dim3(256), 0, stream, xh, wcat, P);
  hipLaunchKernelGGL(k_epilogue, dim3(1024), dim3(256), 0, stream,
                     P, cosg, sing, gq, gk, qh, kh, vth);
  hipLaunchKernelGGL(k_attn, dim3(1024), dim3(256), 0, stream, qh, kh, vth, out);
}

// Round 2
// 480.950 us; speedup vs baseline: 1.6988x; 1.6988x over previous
//
#include <hip/hip_runtime.h>
#include <stdint.h>

typedef _Float16 f16;
typedef _Float16 half8 __attribute__((ext_vector_type(8)));
typedef _Float16 half4v __attribute__((ext_vector_type(4)));
typedef float f32x4 __attribute__((ext_vector_type(4)));

#define DEV static __device__ __forceinline__

DEV f32x4 mfma16(half8 a, half8 b, f32x4 c) {
  return __builtin_amdgcn_mfma_f32_16x16x32_f16(a, b, c, 0, 0, 0);
}

// Problem constants: B=2, S=2048, DIM=1024, H=16, D=64, B1=B2=8, F=32, ITERS=2
// seq position s = g*64 + i*8 + j ; kv position = f*64 + k*8 + l
// Packed L/R slices: slice(bh,g) base = (bh*528 + g(g+1)/2) * 512 elems.

// ---------------- K1: cast x, wq|wk|wv -> fp16 ----------------
__global__ __launch_bounds__(256) void k_cast(
    const float* __restrict__ x, const float* __restrict__ wq,
    const float* __restrict__ wk, const float* __restrict__ wv,
    f16* __restrict__ xh, f16* __restrict__ wcat) {
  const int64_t nx4 = 4194304 / 4;
  const int64_t nw4 = 1048576 / 4;
  int64_t stride = (int64_t)gridDim.x * blockDim.x;
  for (int64_t i = (int64_t)blockIdx.x * blockDim.x + threadIdx.x;
       i < nx4 + 3 * nw4; i += stride) {
    const float* src; f16* dst; int64_t off;
    if (i < nx4) { src = x; dst = xh; off = i; }
    else {
      int64_t r = i - nx4;
      int ws_ = (int)(r / nw4);
      off = r - (int64_t)ws_ * nw4;
      src = (ws_ == 0) ? wq : ((ws_ == 1) ? wk : wv);
      dst = wcat + (int64_t)ws_ * 1048576;
    }
    float4 v = ((const float4*)src)[off];
    half4v hh; hh[0] = (f16)v.x; hh[1] = (f16)v.y; hh[2] = (f16)v.z; hh[3] = (f16)v.w;
    ((half4v*)dst)[off] = hh;
  }
}

// ---------------- K2: P[4096][3072] = xh[4096][1024] @ wcat[3072][1024]^T ----
__global__ __launch_bounds__(256) void k_gemm(
    const f16* __restrict__ A, const f16* __restrict__ Bm,
    float* __restrict__ P) {
  __shared__ f16 As[128 * 72];
  __shared__ f16 Bs[128 * 72];
  const int t = threadIdx.x;
  const int wave = t >> 6, lane = t & 63, quad = lane >> 4, ln = lane & 15;
  const int tM = blockIdx.x / 24, tN = blockIdx.x % 24;
  const int wm = wave >> 1, wn = wave & 1;
  f32x4 acc[4][4];
#pragma unroll
  for (int a = 0; a < 4; ++a)
#pragma unroll
    for (int b = 0; b < 4; ++b) { f32x4 z = {0.f, 0.f, 0.f, 0.f}; acc[a][b] = z; }
  const int r = t >> 1, hf = t & 1;
  const f16* Ag = A + (int64_t)(tM * 128 + r) * 1024 + hf * 32;
  const f16* Bg = Bm + (int64_t)(tN * 128 + r) * 1024 + hf * 32;
  f16* Asw = &As[r * 72 + hf * 32];
  f16* Bsw = &Bs[r * 72 + hf * 32];
  for (int kt = 0; kt < 16; ++kt) {
    half8 a0 = *(const half8*)(Ag + kt * 64);
    half8 a1 = *(const half8*)(Ag + kt * 64 + 8);
    half8 a2 = *(const half8*)(Ag + kt * 64 + 16);
    half8 a3 = *(const half8*)(Ag + kt * 64 + 24);
    half8 b0 = *(const half8*)(Bg + kt * 64);
    half8 b1 = *(const half8*)(Bg + kt * 64 + 8);
    half8 b2 = *(const half8*)(Bg + kt * 64 + 16);
    half8 b3 = *(const half8*)(Bg + kt * 64 + 24);
    __syncthreads();
    *(half8*)(Asw) = a0; *(half8*)(Asw + 8) = a1;
    *(half8*)(Asw + 16) = a2; *(half8*)(Asw + 24) = a3;
    *(half8*)(Bsw) = b0; *(half8*)(Bsw + 8) = b1;
    *(half8*)(Bsw + 16) = b2; *(half8*)(Bsw + 24) = b3;
    __syncthreads();
#pragma unroll
    for (int ks = 0; ks < 2; ++ks) {
      half8 bf[4];
#pragma unroll
      for (int tn = 0; tn < 4; ++tn)
        bf[tn] = *(const half8*)&Bs[(wn * 64 + tn * 16 + ln) * 72 + ks * 32 + quad * 8];
#pragma unroll
      for (int tm = 0; tm < 4; ++tm) {
        half8 af = *(const half8*)&As[(wm * 64 + tm * 16 + ln) * 72 + ks * 32 + quad * 8];
#pragma unroll
        for (int tn = 0; tn < 4; ++tn)
          acc[tm][tn] = mfma16(af, bf[tn], acc[tm][tn]);
      }
    }
  }
#pragma unroll
  for (int tm = 0; tm < 4; ++tm)
#pragma unroll
    for (int tn = 0; tn < 4; ++tn)
#pragma unroll
      for (int r2 = 0; r2 < 4; ++r2) {
        int row = tM * 128 + wm * 64 + tm * 16 + quad * 4 + r2;
        int col = tN * 128 + wn * 64 + tn * 16 + ln;
        P[(int64_t)row * 3072 + col] = acc[tm][tn][r2];
      }
}

// ---------------- K3: rmsnorm+rope+scale for q,k; v -> transposed fp16 ------
__global__ __launch_bounds__(256) void k_epilogue(
    const float* __restrict__ P, const float* __restrict__ cosg,
    const float* __restrict__ sing, const float* __restrict__ gq,
    const float* __restrict__ gk, f16* __restrict__ qh,
    f16* __restrict__ kh, f16* __restrict__ vth) {
  __shared__ f16 vbuf[64 * 72];
  const int t = threadIdx.x;
  const int bid = blockIdx.x;
  const int st = bid & 31, h = (bid >> 5) & 15, b = bid >> 9;
  const int r = t >> 2, qt = t & 3, c0 = qt * 16;
  const int s = st * 64 + r;
  const int64_t rowbase = (int64_t)(b * 2048 + s) * 3072;
  const float scale = 0.35355339059327373f;  // 64^-0.25
#pragma unroll
  for (int m = 0; m < 2; ++m) {
    const float* gv = (m == 0) ? gq : gk;
    const int colbase = m * 1024 + h * 64 + c0;
    float xv[16];
#pragma unroll
    for (int c = 0; c < 4; ++c) {
      float4 v4 = *(const float4*)&P[rowbase + colbase + c * 4];
      xv[c * 4 + 0] = v4.x; xv[c * 4 + 1] = v4.y;
      xv[c * 4 + 2] = v4.z; xv[c * 4 + 3] = v4.w;
    }
    float ss = 0.f;
#pragma unroll
    for (int c = 0; c < 16; ++c) ss += xv[c] * xv[c];
    ss += __shfl_xor(ss, 1, 64);
    ss += __shfl_xor(ss, 2, 64);
    float rs = rsqrtf(ss * (1.f / 64.f) + 1e-6f);
    alignas(16) f16 res[16];
#pragma unroll
    for (int ci = 0; ci < 16; ci += 2) {
      int d0 = c0 + ci, d1 = d0 + 1;
      float av = xv[ci] * rs * gv[d0];
      float bv = xv[ci + 1] * rs * gv[d1];
      float c0v = cosg[s * 64 + d0], c1v = cosg[s * 64 + d1];
      float s0v = sing[s * 64 + d0], s1v = sing[s * 64 + d1];
      res[ci]     = (f16)((av * c0v - bv * s0v) * scale);
      res[ci + 1] = (f16)((bv * c1v + av * s1v) * scale);
    }
    f16* dst = ((m == 0) ? qh : kh) + (int64_t)((b * 16 + h) * 2048 + s) * 64 + c0;
    *(half8*)dst = *(const half8*)&res[0];
    *(half8*)(dst + 8) = *(const half8*)&res[8];
  }
  {
    const int colbase = 2048 + h * 64 + c0;
#pragma unroll
    for (int c = 0; c < 4; ++c) {
      float4 v4 = *(const float4*)&P[rowbase + colbase + c * 4];
      vbuf[(c0 + c * 4 + 0) * 72 + r] = (f16)v4.x;
      vbuf[(c0 + c * 4 + 1) * 72 + r] = (f16)v4.y;
      vbuf[(c0 + c * 4 + 2) * 72 + r] = (f16)v4.z;
      vbuf[(c0 + c * 4 + 3) * 72 + r] = (f16)v4.w;
    }
    __syncthreads();
    const int d = t >> 2, sc = qt * 16;
    alignas(16) f16 tmp[16];
#pragma unroll
    for (int ci = 0; ci < 16; ++ci) tmp[ci] = vbuf[d * 72 + sc + ci];
    f16* dst = vth + (int64_t)((b * 16 + h) * 64 + d) * 2048 + st * 64 + sc;
    *(half8*)dst = *(const half8*)&tmp[0];
    *(half8*)(dst + 8) = *(const half8*)&tmp[8];
  }
}

// ---------------- K4: phase kernel (one iteration's R/bL for a 4-f chunk) ---
// S2 swizzled score layout: element (i,j,k,l) at [609l + 73k + 9j + i]
__global__ __launch_bounds__(256) void k_phase(
    const f16* __restrict__ qh, const f16* __restrict__ kh,
    float* __restrict__ Lg, f16* __restrict__ Rg, int iter) {
  __shared__ f16 qs[64 * 72];
  __shared__ f16 kvs[64 * 72];
  __shared__ float S2[4848];
  __shared__ float Lbuf[528];
  __shared__ f16 Rbuf[576];
  __shared__ float cLb[64];

  const int t = threadIdx.x;
  const int wave = t >> 6, lane = t & 63, quad = lane >> 4, ln = lane & 15;
  const int fc = blockIdx.x & 7;
  const int g = 31 - ((blockIdx.x >> 3) & 31);
  const int bh = blockIdx.x >> 8;
  const int f0 = fc * 4;
  if (f0 > g) return;
  const int f1 = (f0 + 4 < g + 1) ? f0 + 4 : g + 1;

  const f16* qg = qh + (int64_t)(bh * 2048 + g * 64) * 64;
  const f16* kb = kh + (int64_t)bh * 2048 * 64;
  const int64_t sbase = ((int64_t)bh * 528 + ((g * (g + 1)) >> 1)) * 512;
  float* Lp = Lg + sbase;
  f16* Rp = Rg + sbase;

  { // stage q_g
    const int r = t >> 2, c0 = (t & 3) * 16;
    *(half8*)&qs[r * 72 + c0] = *(const half8*)&qg[r * 64 + c0];
    *(half8*)&qs[r * 72 + c0 + 8] = *(const half8*)&qg[r * 64 + c0 + 8];
  }

  const int cI = wave * 16 + ln;
  const int cpart = 609 * (cI & 7) + 73 * (cI >> 3);

  for (int f = f0; f < f1; ++f) {
    __syncthreads();
    { // stage k_f
      const int r = t >> 2, c0 = (t & 3) * 16;
      const f16* src = kb + (int64_t)f * 64 * 64;
      *(half8*)&kvs[r * 72 + c0] = *(const half8*)&src[r * 64 + c0];
      *(half8*)&kvs[r * 72 + c0 + 8] = *(const half8*)&src[r * 64 + c0 + 8];
    }
    if (iter) { // stage L[f] -> Lbuf[j*66 + k*8 + i]
      const int o = 2 * t;
      *(float2*)&Lbuf[(o >> 6) * 66 + (o & 63)] = *(const float2*)&Lp[f * 512 + o];
    }
    __syncthreads();
    { // S = q_g k_f^T -> S2 (swizzled)
      f32x4 acc[4];
#pragma unroll
      for (int tm = 0; tm < 4; ++tm) { f32x4 z = {0.f, 0.f, 0.f, 0.f}; acc[tm] = z; }
#pragma unroll
      for (int ks = 0; ks < 2; ++ks) {
        half8 b8 = *(const half8*)&kvs[(wave * 16 + ln) * 72 + ks * 32 + quad * 8];
#pragma unroll
        for (int tm = 0; tm < 4; ++tm) {
          half8 a8 = *(const half8*)&qs[(tm * 16 + ln) * 72 + ks * 32 + quad * 8];
          acc[tm] = mfma16(a8, b8, acc[tm]);
        }
      }
#pragma unroll
      for (int tm = 0; tm < 4; ++tm)
#pragma unroll
        for (int r2 = 0; r2 < 4; ++r2) {
          const int rI = tm * 16 + quad * 4 + r2;
          S2[cpart + 9 * (rI & 7) + (rI >> 3)] = acc[tm][r2];
        }
    }
    __syncthreads();
    { // R-step
      float va[2];
#pragma unroll
      for (int e = 0; e < 2; ++e) {
        const int o = t + e * 256;
        const int k_ = o >> 6, j = (o >> 3) & 7, l = o & 7;
        if (iter == 0) {
          va[e] = S2[609 * l + 74 * k_ + 9 * j] * (1.f / (1.f + 1e-6f));
        } else {
          float bR = 0.f, cR = 0.f;
          const float* Lrow = &Lbuf[j * 66 + k_ * 8];
          const float* Sp = &S2[609 * l + 73 * k_ + 9 * j];
#pragma unroll
          for (int i = 0; i < 8; ++i) {
            float Lv = Lrow[i];
            cR += Lv;
            bR += Lv * Sp[i];
          }
          va[e] = bR / (cR + 1e-6f);
        }
      }
#pragma unroll
      for (int e = 0; e < 2; ++e) {
        const int o = t + e * 256;
        const int k_ = o >> 6, j = (o >> 3) & 7, l = o & 7;
        float m = va[e];
        m = fmaxf(m, __shfl_xor(m, 1, 64));
        m = fmaxf(m, __shfl_xor(m, 2, 64));
        m = fmaxf(m, __shfl_xor(m, 4, 64));
        float ex = __expf(va[e] - m);
        float sm = ex;
        sm += __shfl_xor(sm, 1, 64);
        sm += __shfl_xor(sm, 2, 64);
        sm += __shfl_xor(sm, 4, 64);
        float rr = ex / sm;
        Rbuf[k_ * 72 + j * 8 + l] = (f16)rr;
        if (iter) Rp[f * 512 + o] = (f16)rr;
        float rl = rr * __logf(fmaxf(rr, 1e-30f));
        rl += __shfl_xor(rl, 1, 64);
        rl += __shfl_xor(rl, 2, 64);
        rl += __shfl_xor(rl, 4, 64);
        if (l == 0) cLb[j * 8 + k_] = rl;
      }
    }
    __syncthreads();
    { // bL-step -> Lg logits
#pragma unroll
      for (int e = 0; e < 2; ++e) {
        const int o = t + e * 256;
        const int j = o >> 6, k_ = (o >> 3) & 7, i = o & 7;
        const f16* Rr = &Rbuf[k_ * 72 + j * 8];
        const float* Sp = &S2[73 * k_ + 9 * j + i];
        float bL = 0.f;
#pragma unroll
        for (int l = 0; l < 8; ++l) bL += (float)Rr[l] * Sp[609 * l];
        Lp[f * 512 + o] = bL - cLb[j * 8 + k_];
      }
    }
  }
}

// ---------------- K5: joint softmax over (f<=g, k) per (j,i) row ------------
__global__ __launch_bounds__(256) void k_softmax(float* __restrict__ Lg) {
  __shared__ float Ls[32 * 546];
  const int t = threadIdx.x;
  const int g = blockIdx.x & 31, bh = blockIdx.x >> 5;
  float* Lp = Lg + ((int64_t)bh * 528 + ((g * (g + 1)) >> 1)) * 512;
  for (int f = 0; f <= g; ++f) {
    const int o = 2 * t;
    *(float2*)&Ls[f * 546 + (o >> 6) * 68 + (o & 63)] = *(const float2*)&Lp[f * 512 + o];
  }
  __syncthreads();
  const int p = t >> 2, sub = t & 3;
  const int j = p >> 3, i = p & 7;
  const int base = j * 68 + i;
  float mx = -1e30f;
  for (int f = sub; f <= g; f += 4)
#pragma unroll
    for (int k_ = 0; k_ < 8; ++k_)
      mx = fmaxf(mx, Ls[f * 546 + base + k_ * 8]);
  mx = fmaxf(mx, __shfl_xor(mx, 1, 64));
  mx = fmaxf(mx, __shfl_xor(mx, 2, 64));
  float se = 0.f;
  for (int f = sub; f <= g; f += 4)
#pragma unroll
    for (int k_ = 0; k_ < 8; ++k_)
      se += __expf(Ls[f * 546 + base + k_ * 8] - mx);
  se += __shfl_xor(se, 1, 64);
  se += __shfl_xor(se, 2, 64);
  const float inv = 1.f / se;
  for (int f = sub; f <= g; f += 4)
#pragma unroll
    for (int k_ = 0; k_ < 8; ++k_) {
      const int idx = f * 546 + base + k_ * 8;
      Ls[idx] = __expf(Ls[idx] - mx) * inv;
    }
  __syncthreads();
  for (int f = 0; f <= g; ++f) {
    const int o = 2 * t;
    *(float2*)&Lp[f * 512 + o] = *(const float2*)&Ls[f * 546 + (o >> 6) * 68 + (o & 63)];
  }
}

// ---------------- K6: output pass: out = sum_f (L*R)_f @ v_f ----------------
__global__ __launch_bounds__(256) void k_out(
    const float* __restrict__ Lg, const f16* __restrict__ Rg,
    const f16* __restrict__ vth, float* __restrict__ out) {
  __shared__ f16 vbuf[64 * 72];
  __shared__ float Lbuf[528];
  __shared__ f16 Rbuf[576];
  const int t = threadIdx.x;
  const int wave = t >> 6, lane = t & 63, quad = lane >> 4, ln = lane & 15;
  const int g = 31 - (blockIdx.x & 31), bh = blockIdx.x >> 5;
  const f16* vb = vth + (int64_t)bh * 64 * 2048;
  const int64_t sbase = ((int64_t)bh * 528 + ((g * (g + 1)) >> 1)) * 512;
  const float* Lp = Lg + sbase;
  const f16* Rp = Rg + sbase;
  f32x4 oacc[4];
#pragma unroll
  for (int tm = 0; tm < 4; ++tm) { f32x4 z = {0.f, 0.f, 0.f, 0.f}; oacc[tm] = z; }
  for (int f = 0; f <= g; ++f) {
    __syncthreads();
    { // stage v_f ([d][s] layout: rows contiguous)
      const int r = t >> 2, c0 = (t & 3) * 16;
      const f16* src = vb + f * 64;
      *(half8*)&vbuf[r * 72 + c0] = *(const half8*)&src[(int64_t)r * 2048 + c0];
      *(half8*)&vbuf[r * 72 + c0 + 8] = *(const half8*)&src[(int64_t)r * 2048 + c0 + 8];
    }
    { // stage L[f], R[f]
      const int o = 2 * t;
      *(float2*)&Lbuf[(o >> 6) * 66 + (o & 63)] = *(const float2*)&Lp[f * 512 + o];
      *(uint32_t*)&Rbuf[(o >> 6) * 72 + (o & 63)] = *(const uint32_t*)&Rp[f * 512 + o];
    }
    __syncthreads();
#pragma unroll
    for (int ks = 0; ks < 2; ++ks) {
      half8 v8 = *(const half8*)&vbuf[(wave * 16 + ln) * 72 + ks * 32 + quad * 8];
      const int k4 = ks * 4 + quad;
#pragma unroll
      for (int tm = 0; tm < 4; ++tm) {
        const int m = tm * 16 + ln;
        const int i = m >> 3, j = m & 7;
        const float Lval = Lbuf[j * 66 + k4 * 8 + i];
        half8 r8 = *(const half8*)&Rbuf[k4 * 72 + j * 8];
        const f16 Lh = (f16)Lval;
        half8 w8;
#pragma unroll
        for (int l = 0; l < 8; ++l) w8[l] = r8[l] * Lh;
        oacc[tm] = mfma16(w8, v8, oacc[tm]);
      }
    }
  }
  float* ob = out + (int64_t)((bh >> 4) * 2048 + g * 64) * 1024 + (bh & 15) * 64;
#pragma unroll
  for (int tm = 0; tm < 4; ++tm)
#pragma unroll
    for (int r2 = 0; r2 < 4; ++r2)
      ob[(int64_t)(tm * 16 + quad * 4 + r2) * 1024 + wave * 16 + ln] = oacc[tm][r2];
}

// ---------------------------------------------------------------------------
extern "C" void kernel_launch(void* const* d_in, const int* in_sizes, int n_in,
                              void* d_out, int out_size, void* d_ws, size_t ws_size,
                              hipStream_t stream) {
  const float* x    = (const float*)d_in[0];
  const float* cosg = (const float*)d_in[1];
  const float* sing = (const float*)d_in[2];
  const float* wq   = (const float*)d_in[3];
  const float* wk   = (const float*)d_in[4];
  const float* wv   = (const float*)d_in[5];
  const float* gq   = (const float*)d_in[6];
  const float* gk   = (const float*)d_in[7];
  float* out = (float*)d_out;

  char* ws = (char*)d_ws;
  f16*   xh   = (f16*)(ws);                       // 8,388,608 B
  f16*   wcat = (f16*)(ws + 8388608);             // 6,291,456 B
  float* P    = (float*)(ws + 14680064);          // 50,331,648 B (dead after K3)
  f16*   Rg   = (f16*)(ws + 14680064);            // 17,301,504 B (aliases P)
  f16*   qh   = (f16*)(ws + 65011712);            // 8,388,608 B
  f16*   kh   = (f16*)(ws + 73400320);            // 8,388,608 B
  f16*   vth  = (f16*)(ws + 81788928);            // 8,388,608 B
  float* Lg   = (float*)(ws + 90177536);          // 34,603,008 B -> end ~119 MB

  hipLaunchKernelGGL(k_cast, dim3(1024), dim3(256), 0, stream, x, wq, wk, wv, xh, wcat);
  hipLaunchKernelGGL(k_gemm, dim3(768), dim3(256), 0, stream, xh, wcat, P);
  hipLaunchKernelGGL(k_epilogue, dim3(1024), dim3(256), 0, stream,
                     P, cosg, sing, gq, gk, qh, kh, vth);
  hipLaunchKernelGGL(k_phase, dim3(8192), dim3(256), 0, stream, qh, kh, Lg, Rg, 0);
  hipLaunchKernelGGL(k_softmax, dim3(1024), dim3(256), 0, stream, Lg);
  hipLaunchKernelGGL(k_phase, dim3(8192), dim3(256), 0, stream, qh, kh, Lg, Rg, 1);
  hipLaunchKernelGGL(k_softmax, dim3(1024), dim3(256), 0, stream, Lg);
  hipLaunchKernelGGL(k_out, dim3(1024), dim3(256), 0, stream, Lg, Rg, vth, out);
}

// Round 3
// 391.066 us; speedup vs baseline: 2.0893x; 1.2298x over previous
//
#include <hip/hip_runtime.h>
#include <stdint.h>

typedef _Float16 f16;
typedef _Float16 half8 __attribute__((ext_vector_type(8)));
typedef _Float16 half4v __attribute__((ext_vector_type(4)));
typedef float f32x4 __attribute__((ext_vector_type(4)));

#define DEV static __device__ __forceinline__

DEV f32x4 mfma16(half8 a, half8 b, f32x4 c) {
  return __builtin_amdgcn_mfma_f32_16x16x32_f16(a, b, c, 0, 0, 0);
}

// Problem constants: B=2, S=2048, DIM=1024, H=16, D=64, B1=B2=8, F=32, ITERS=2
// seq position s = g*64 + i*8 + j ; kv position = f*64 + k*8 + l
// Packed L/R slices: slice(bh,g,f) base = (bh*528 + g(g+1)/2 + f) * 512 elems.
// L slice layout: o = j*64 + k*8 + i ; R slice layout: o = k*64 + j*8 + l.
// stats layout: stats[((bh*32+g)*64 + j*8+i)*2 + {0:max,1:1/sum}]

// ---------------- K1: cast x, wq|wk|wv -> fp16 ----------------
__global__ __launch_bounds__(256) void k_cast(
    const float* __restrict__ x, const float* __restrict__ wq,
    const float* __restrict__ wk, const float* __restrict__ wv,
    f16* __restrict__ xh, f16* __restrict__ wcat) {
  const int64_t nx4 = 4194304 / 4;
  const int64_t nw4 = 1048576 / 4;
  int64_t stride = (int64_t)gridDim.x * blockDim.x;
  for (int64_t i = (int64_t)blockIdx.x * blockDim.x + threadIdx.x;
       i < nx4 + 3 * nw4; i += stride) {
    const float* src; f16* dst; int64_t off;
    if (i < nx4) { src = x; dst = xh; off = i; }
    else {
      int64_t r = i - nx4;
      int ws_ = (int)(r / nw4);
      off = r - (int64_t)ws_ * nw4;
      src = (ws_ == 0) ? wq : ((ws_ == 1) ? wk : wv);
      dst = wcat + (int64_t)ws_ * 1048576;
    }
    float4 v = ((const float4*)src)[off];
    half4v hh; hh[0] = (f16)v.x; hh[1] = (f16)v.y; hh[2] = (f16)v.z; hh[3] = (f16)v.w;
    ((half4v*)dst)[off] = hh;
  }
}

// ---------------- K2: P[4096][3072] = xh[4096][1024] @ wcat[3072][1024]^T ----
__global__ __launch_bounds__(256) void k_gemm(
    const f16* __restrict__ A, const f16* __restrict__ Bm,
    float* __restrict__ P) {
  __shared__ f16 As[128 * 72];
  __shared__ f16 Bs[128 * 72];
  const int t = threadIdx.x;
  const int wave = t >> 6, lane = t & 63, quad = lane >> 4, ln = lane & 15;
  const int tM = blockIdx.x / 24, tN = blockIdx.x % 24;
  const int wm = wave >> 1, wn = wave & 1;
  f32x4 acc[4][4];
#pragma unroll
  for (int a = 0; a < 4; ++a)
#pragma unroll
    for (int b = 0; b < 4; ++b) { f32x4 z = {0.f, 0.f, 0.f, 0.f}; acc[a][b] = z; }
  const int r = t >> 1, hf = t & 1;
  const f16* Ag = A + (int64_t)(tM * 128 + r) * 1024 + hf * 32;
  const f16* Bg = Bm + (int64_t)(tN * 128 + r) * 1024 + hf * 32;
  f16* Asw = &As[r * 72 + hf * 32];
  f16* Bsw = &Bs[r * 72 + hf * 32];
  for (int kt = 0; kt < 16; ++kt) {
    half8 a0 = *(const half8*)(Ag + kt * 64);
    half8 a1 = *(const half8*)(Ag + kt * 64 + 8);
    half8 a2 = *(const half8*)(Ag + kt * 64 + 16);
    half8 a3 = *(const half8*)(Ag + kt * 64 + 24);
    half8 b0 = *(const half8*)(Bg + kt * 64);
    half8 b1 = *(const half8*)(Bg + kt * 64 + 8);
    half8 b2 = *(const half8*)(Bg + kt * 64 + 16);
    half8 b3 = *(const half8*)(Bg + kt * 64 + 24);
    __syncthreads();
    *(half8*)(Asw) = a0; *(half8*)(Asw + 8) = a1;
    *(half8*)(Asw + 16) = a2; *(half8*)(Asw + 24) = a3;
    *(half8*)(Bsw) = b0; *(half8*)(Bsw + 8) = b1;
    *(half8*)(Bsw + 16) = b2; *(half8*)(Bsw + 24) = b3;
    __syncthreads();
#pragma unroll
    for (int ks = 0; ks < 2; ++ks) {
      half8 bf[4];
#pragma unroll
      for (int tn = 0; tn < 4; ++tn)
        bf[tn] = *(const half8*)&Bs[(wn * 64 + tn * 16 + ln) * 72 + ks * 32 + quad * 8];
#pragma unroll
      for (int tm = 0; tm < 4; ++tm) {
        half8 af = *(const half8*)&As[(wm * 64 + tm * 16 + ln) * 72 + ks * 32 + quad * 8];
#pragma unroll
        for (int tn = 0; tn < 4; ++tn)
          acc[tm][tn] = mfma16(af, bf[tn], acc[tm][tn]);
      }
    }
  }
#pragma unroll
  for (int tm = 0; tm < 4; ++tm)
#pragma unroll
    for (int tn = 0; tn < 4; ++tn)
#pragma unroll
      for (int r2 = 0; r2 < 4; ++r2) {
        int row = tM * 128 + wm * 64 + tm * 16 + quad * 4 + r2;
        int col = tN * 128 + wn * 64 + tn * 16 + ln;
        P[(int64_t)row * 3072 + col] = acc[tm][tn][r2];
      }
}

// ---------------- K3: rmsnorm+rope+scale for q,k; v -> transposed fp16 ------
__global__ __launch_bounds__(256) void k_epilogue(
    const float* __restrict__ P, const float* __restrict__ cosg,
    const float* __restrict__ sing, const float* __restrict__ gq,
    const float* __restrict__ gk, f16* __restrict__ qh,
    f16* __restrict__ kh, f16* __restrict__ vth) {
  __shared__ f16 vbuf[64 * 72];
  const int t = threadIdx.x;
  const int bid = blockIdx.x;
  const int st = bid & 31, h = (bid >> 5) & 15, b = bid >> 9;
  const int r = t >> 2, qt = t & 3, c0 = qt * 16;
  const int s = st * 64 + r;
  const int64_t rowbase = (int64_t)(b * 2048 + s) * 3072;
  const float scale = 0.35355339059327373f;  // 64^-0.25
#pragma unroll
  for (int m = 0; m < 2; ++m) {
    const float* gv = (m == 0) ? gq : gk;
    const int colbase = m * 1024 + h * 64 + c0;
    float xv[16];
#pragma unroll
    for (int c = 0; c < 4; ++c) {
      float4 v4 = *(const float4*)&P[rowbase + colbase + c * 4];
      xv[c * 4 + 0] = v4.x; xv[c * 4 + 1] = v4.y;
      xv[c * 4 + 2] = v4.z; xv[c * 4 + 3] = v4.w;
    }
    float ss = 0.f;
#pragma unroll
    for (int c = 0; c < 16; ++c) ss += xv[c] * xv[c];
    ss += __shfl_xor(ss, 1, 64);
    ss += __shfl_xor(ss, 2, 64);
    float rs = rsqrtf(ss * (1.f / 64.f) + 1e-6f);
    alignas(16) f16 res[16];
#pragma unroll
    for (int ci = 0; ci < 16; ci += 2) {
      int d0 = c0 + ci, d1 = d0 + 1;
      float av = xv[ci] * rs * gv[d0];
      float bv = xv[ci + 1] * rs * gv[d1];
      float c0v = cosg[s * 64 + d0], c1v = cosg[s * 64 + d1];
      float s0v = sing[s * 64 + d0], s1v = sing[s * 64 + d1];
      res[ci]     = (f16)((av * c0v - bv * s0v) * scale);
      res[ci + 1] = (f16)((bv * c1v + av * s1v) * scale);
    }
    f16* dst = ((m == 0) ? qh : kh) + (int64_t)((b * 16 + h) * 2048 + s) * 64 + c0;
    *(half8*)dst = *(const half8*)&res[0];
    *(half8*)(dst + 8) = *(const half8*)&res[8];
  }
  {
    const int colbase = 2048 + h * 64 + c0;
#pragma unroll
    for (int c = 0; c < 4; ++c) {
      float4 v4 = *(const float4*)&P[rowbase + colbase + c * 4];
      vbuf[(c0 + c * 4 + 0) * 72 + r] = (f16)v4.x;
      vbuf[(c0 + c * 4 + 1) * 72 + r] = (f16)v4.y;
      vbuf[(c0 + c * 4 + 2) * 72 + r] = (f16)v4.z;
      vbuf[(c0 + c * 4 + 3) * 72 + r] = (f16)v4.w;
    }
    __syncthreads();
    const int d = t >> 2, sc = qt * 16;
    alignas(16) f16 tmp[16];
#pragma unroll
    for (int ci = 0; ci < 16; ++ci) tmp[ci] = vbuf[d * 72 + sc + ci];
    f16* dst = vth + (int64_t)((b * 16 + h) * 64 + d) * 2048 + st * 64 + sc;
    *(half8*)dst = *(const half8*)&tmp[0];
    *(half8*)(dst + 8) = *(const half8*)&tmp[8];
  }
}

// ---------------- K4: phase kernel — ONE block per (bh,g,f) -----------------
// q/k MFMA fragments loaded direct from global (16B/lane, L2-resident).
// S2 swizzled score layout: element (i,j,k,l) at [609l + 73k + 9j + i].
// LDS ~23 KB -> 6 blocks/CU. Two barriers per block total.
__global__ __launch_bounds__(256) void k_phase(
    const f16* __restrict__ qh, const f16* __restrict__ kh,
    float* __restrict__ Lg, f16* __restrict__ Rg,
    const float* __restrict__ stats, int iter) {
  __shared__ float S2[4848];       // 19392 B
  __shared__ float Lbuf[528];      // 2112 B (stride 66 per j)
  __shared__ f16 Rbuf[576];        // 1152 B (stride 72 per k)
  __shared__ float cLb[64];

  const int t = threadIdx.x;
  const int wave = t >> 6, lane = t & 63, quad = lane >> 4, ln = lane & 15;
  const int bh = blockIdx.x / 528;
  const int rem = blockIdx.x - bh * 528;
  int g = (int)((sqrtf(8.f * (float)rem + 1.f) - 1.f) * 0.5f);
  while ((g + 1) * (g + 2) / 2 <= rem) ++g;
  while (g * (g + 1) / 2 > rem) --g;
  const int f = rem - g * (g + 1) / 2;

  const f16* qg = qh + (int64_t)(bh * 2048 + g * 64) * 64;
  const f16* kf = kh + (int64_t)(bh * 2048 + f * 64) * 64;
  const int64_t sbase = ((int64_t)bh * 528 + ((g * (g + 1)) >> 1) + f) * 512;
  float* Lp = Lg + sbase;
  f16* Rp = Rg + sbase;

  // --- QK^T fragments direct from global; wave w = column strip nt=w ---
  half8 bfr[2], afr[2][4];
#pragma unroll
  for (int ks = 0; ks < 2; ++ks) {
    bfr[ks] = *(const half8*)&kf[(wave * 16 + ln) * 64 + ks * 32 + quad * 8];
#pragma unroll
    for (int mt = 0; mt < 4; ++mt)
      afr[ks][mt] = *(const half8*)&qg[(mt * 16 + ln) * 64 + ks * 32 + quad * 8];
  }
  // stage L[f] probs (iter2) while fragment loads are in flight
  if (iter) {
    const int o = 2 * t;
    float2 lv = *(const float2*)&Lp[o];
    const int si = ((o >> 6) << 3) | (o & 7);
    const float* st = &stats[((size_t)(bh * 32 + g) * 64 + si) * 2];
    float p0 = __expf(lv.x - st[0]) * st[1];
    float p1 = __expf(lv.y - st[2]) * st[3];
    Lbuf[(o >> 6) * 66 + (o & 63)]     = p0;
    Lbuf[(o >> 6) * 66 + (o & 63) + 1] = p1;
  }
  {
    f32x4 acc[4];
#pragma unroll
    for (int mt = 0; mt < 4; ++mt) { f32x4 z = {0.f, 0.f, 0.f, 0.f}; acc[mt] = z; }
#pragma unroll
    for (int ks = 0; ks < 2; ++ks)
#pragma unroll
      for (int mt = 0; mt < 4; ++mt)
        acc[mt] = mfma16(afr[ks][mt], bfr[ks], acc[mt]);
    const int n = wave * 16 + ln;
    const int cpart = 609 * (n & 7) + 73 * (n >> 3);
#pragma unroll
    for (int mt = 0; mt < 4; ++mt)
#pragma unroll
      for (int r2 = 0; r2 < 4; ++r2) {
        const int m = mt * 16 + quad * 4 + r2;
        S2[cpart + 9 * (m & 7) + (m >> 3)] = acc[mt][r2];
      }
  }
  __syncthreads();
  { // R-step: bR,cR -> softmax over l -> Rbuf (+Rg iter2), cLb
    float va[2];
#pragma unroll
    for (int e = 0; e < 2; ++e) {
      const int o = t + e * 256;
      const int k_ = o >> 6, j = (o >> 3) & 7, l = o & 7;
      if (iter == 0) {
        va[e] = S2[609 * l + 74 * k_ + 9 * j] * (1.f / (1.f + 1e-6f));
      } else {
        float bR = 0.f, cR = 0.f;
        const float* Lrow = &Lbuf[j * 66 + k_ * 8];
        const float* Sp = &S2[609 * l + 73 * k_ + 9 * j];
#pragma unroll
        for (int i = 0; i < 8; ++i) {
          float Lv = Lrow[i];
          cR += Lv;
          bR += Lv * Sp[i];
        }
        va[e] = bR / (cR + 1e-6f);
      }
    }
#pragma unroll
    for (int e = 0; e < 2; ++e) {
      const int o = t + e * 256;
      const int k_ = o >> 6, j = (o >> 3) & 7, l = o & 7;
      float m = va[e];
      m = fmaxf(m, __shfl_xor(m, 1, 64));
      m = fmaxf(m, __shfl_xor(m, 2, 64));
      m = fmaxf(m, __shfl_xor(m, 4, 64));
      float ex = __expf(va[e] - m);
      float sm = ex;
      sm += __shfl_xor(sm, 1, 64);
      sm += __shfl_xor(sm, 2, 64);
      sm += __shfl_xor(sm, 4, 64);
      float rr = ex / sm;
      Rbuf[k_ * 72 + j * 8 + l] = (f16)rr;
      if (iter) Rp[o] = (f16)rr;
      float rl = rr * __logf(fmaxf(rr, 1e-30f));
      rl += __shfl_xor(rl, 1, 64);
      rl += __shfl_xor(rl, 2, 64);
      rl += __shfl_xor(rl, 4, 64);
      if (l == 0) cLb[j * 8 + k_] = rl;
    }
  }
  __syncthreads();
  { // bL-step -> raw logits to Lg
#pragma unroll
    for (int e = 0; e < 2; ++e) {
      const int o = t + e * 256;
      const int j = o >> 6, k_ = (o >> 3) & 7, i = o & 7;
      const f16* Rr = &Rbuf[k_ * 72 + j * 8];
      const float* Sp = &S2[73 * k_ + 9 * j + i];
      float bL = 0.f;
#pragma unroll
      for (int l = 0; l < 8; ++l) bL += (float)Rr[l] * Sp[609 * l];
      Lp[o] = bL - cLb[j * 8 + k_];
    }
  }
}

// ---------------- K5: softmax STATS only (max, 1/sum) per (bh,g,(j,i)) ------
__global__ __launch_bounds__(256) void k_stats(
    const float* __restrict__ Lg, float* __restrict__ stats) {
  __shared__ float Ls[32 * 546];
  const int t = threadIdx.x;
  const int g = 31 - (blockIdx.x & 31), bh = blockIdx.x >> 5;
  const float* Lp = Lg + ((int64_t)bh * 528 + ((g * (g + 1)) >> 1)) * 512;
  for (int f = 0; f <= g; ++f) {
    const int o = 2 * t;
    *(float2*)&Ls[f * 546 + (o >> 6) * 68 + (o & 63)] = *(const float2*)&Lp[f * 512 + o];
  }
  __syncthreads();
  const int p = t >> 2, sub = t & 3;
  const int j = p >> 3, i = p & 7;
  const int base = j * 68 + i;
  float mx = -1e30f;
  for (int f = sub; f <= g; f += 4)
#pragma unroll
    for (int k_ = 0; k_ < 8; ++k_)
      mx = fmaxf(mx, Ls[f * 546 + base + k_ * 8]);
  mx = fmaxf(mx, __shfl_xor(mx, 1, 64));
  mx = fmaxf(mx, __shfl_xor(mx, 2, 64));
  float se = 0.f;
  for (int f = sub; f <= g; f += 4)
#pragma unroll
    for (int k_ = 0; k_ < 8; ++k_)
      se += __expf(Ls[f * 546 + base + k_ * 8] - mx);
  se += __shfl_xor(se, 1, 64);
  se += __shfl_xor(se, 2, 64);
  if (sub == 0) {
    float* st = &stats[((size_t)(bh * 32 + g) * 64 + p) * 2];
    st[0] = mx;
    st[1] = 1.f / se;
  }
}

// ---------------- K6: output pass: out = sum_f (L*R)_f @ v_f ----------------
__global__ __launch_bounds__(256) void k_out(
    const float* __restrict__ Lg, const f16* __restrict__ Rg,
    const f16* __restrict__ vth, const float* __restrict__ stats,
    float* __restrict__ out) {
  __shared__ f16 vbuf[64 * 72];
  __shared__ float Lbuf[528];
  __shared__ f16 Rbuf[576];
  const int t = threadIdx.x;
  const int wave = t >> 6, lane = t & 63, quad = lane >> 4, ln = lane & 15;
  const int g = 31 - (blockIdx.x & 31), bh = blockIdx.x >> 5;
  const f16* vb = vth + (int64_t)bh * 64 * 2048;
  const int64_t sbase = ((int64_t)bh * 528 + ((g * (g + 1)) >> 1)) * 512;
  const float* Lp = Lg + sbase;
  const f16* Rp = Rg + sbase;
  // per-thread softmax-2 stats for its two staged L elements
  const int o = 2 * t;
  const int si = ((o >> 6) << 3) | (o & 7);
  const float* st = &stats[((size_t)(bh * 32 + g) * 64 + si) * 2];
  const float mx0 = st[0], inv0 = st[1], mx1 = st[2], inv1 = st[3];
  f32x4 oacc[4];
#pragma unroll
  for (int tm = 0; tm < 4; ++tm) { f32x4 z = {0.f, 0.f, 0.f, 0.f}; oacc[tm] = z; }
  for (int f = 0; f <= g; ++f) {
    __syncthreads();
    { // stage v_f ([d][s] layout: rows contiguous)
      const int r = t >> 2, c0 = (t & 3) * 16;
      const f16* src = vb + f * 64;
      *(half8*)&vbuf[r * 72 + c0] = *(const half8*)&src[(int64_t)r * 2048 + c0];
      *(half8*)&vbuf[r * 72 + c0 + 8] = *(const half8*)&src[(int64_t)r * 2048 + c0 + 8];
    }
    { // stage L[f] probs (inline softmax from raw logits), R[f]
      float2 lv = *(const float2*)&Lp[f * 512 + o];
      Lbuf[(o >> 6) * 66 + (o & 63)]     = __expf(lv.x - mx0) * inv0;
      Lbuf[(o >> 6) * 66 + (o & 63) + 1] = __expf(lv.y - mx1) * inv1;
      *(uint32_t*)&Rbuf[(o >> 6) * 72 + (o & 63)] = *(const uint32_t*)&Rp[f * 512 + o];
    }
    __syncthreads();
#pragma unroll
    for (int ks = 0; ks < 2; ++ks) {
      half8 v8 = *(const half8*)&vbuf[(wave * 16 + ln) * 72 + ks * 32 + quad * 8];
      const int k4 = ks * 4 + quad;
#pragma unroll
      for (int tm = 0; tm < 4; ++tm) {
        const int m = tm * 16 + ln;
        const int i = m >> 3, j = m & 7;
        const float Lval = Lbuf[j * 66 + k4 * 8 + i];
        half8 r8 = *(const half8*)&Rbuf[k4 * 72 + j * 8];
        const f16 Lh = (f16)Lval;
        half8 w8;
#pragma unroll
        for (int l = 0; l < 8; ++l) w8[l] = r8[l] * Lh;
        oacc[tm] = mfma16(w8, v8, oacc[tm]);
      }
    }
  }
  float* ob = out + (int64_t)((bh >> 4) * 2048 + g * 64) * 1024 + (bh & 15) * 64;
#pragma unroll
  for (int tm = 0; tm < 4; ++tm)
#pragma unroll
    for (int r2 = 0; r2 < 4; ++r2)
      ob[(int64_t)(tm * 16 + quad * 4 + r2) * 1024 + wave * 16 + ln] = oacc[tm][r2];
}

// ---------------------------------------------------------------------------
extern "C" void kernel_launch(void* const* d_in, const int* in_sizes, int n_in,
                              void* d_out, int out_size, void* d_ws, size_t ws_size,
                              hipStream_t stream) {
  const float* x    = (const float*)d_in[0];
  const float* cosg = (const float*)d_in[1];
  const float* sing = (const float*)d_in[2];
  const float* wq   = (const float*)d_in[3];
  const float* wk   = (const float*)d_in[4];
  const float* wv   = (const float*)d_in[5];
  const float* gq   = (const float*)d_in[6];
  const float* gk   = (const float*)d_in[7];
  float* out = (float*)d_out;

  char* ws = (char*)d_ws;
  f16*   xh     = (f16*)(ws);                     // 8,388,608 B
  f16*   wcat   = (f16*)(ws + 8388608);           // 6,291,456 B
  float* P      = (float*)(ws + 14680064);        // 50,331,648 B (dead after K3)
  f16*   Rg     = (f16*)(ws + 14680064);          // 17,301,504 B (aliases P)
  float* stats1 = (float*)(ws + 31981568);        // 524,288 B (aliases old P)
  float* stats2 = (float*)(ws + 32505856);        // 524,288 B (aliases old P)
  f16*   qh     = (f16*)(ws + 65011712);          // 8,388,608 B
  f16*   kh     = (f16*)(ws + 73400320);          // 8,388,608 B
  f16*   vth    = (f16*)(ws + 81788928);          // 8,388,608 B
  float* Lg     = (float*)(ws + 90177536);        // 34,603,008 B -> end ~119 MB

  hipLaunchKernelGGL(k_cast, dim3(1024), dim3(256), 0, stream, x, wq, wk, wv, xh, wcat);
  hipLaunchKernelGGL(k_gemm, dim3(768), dim3(256), 0, stream, xh, wcat, P);
  hipLaunchKernelGGL(k_epilogue, dim3(1024), dim3(256), 0, stream,
                     P, cosg, sing, gq, gk, qh, kh, vth);
  hipLaunchKernelGGL(k_phase, dim3(16896), dim3(256), 0, stream, qh, kh, Lg, Rg, stats1, 0);
  hipLaunchKernelGGL(k_stats, dim3(1024), dim3(256), 0, stream, Lg, stats1);
  hipLaunchKernelGGL(k_phase, dim3(16896), dim3(256), 0, stream, qh, kh, Lg, Rg, stats1, 1);
  hipLaunchKernelGGL(k_stats, dim3(1024), dim3(256), 0, stream, Lg, stats2);
  hipLaunchKernelGGL(k_out, dim3(1024), dim3(256), 0, stream, Lg, Rg, vth, stats2, out);
}

// Round 4
// 352.530 us; speedup vs baseline: 2.3177x; 1.1093x over previous
//
#include <hip/hip_runtime.h>
#include <stdint.h>

typedef _Float16 f16;
typedef _Float16 half8 __attribute__((ext_vector_type(8)));
typedef _Float16 half4v __attribute__((ext_vector_type(4)));
typedef float f32x4 __attribute__((ext_vector_type(4)));

#define DEV static __device__ __forceinline__

DEV f32x4 mfma16(half8 a, half8 b, f32x4 c) {
  return __builtin_amdgcn_mfma_f32_16x16x32_f16(a, b, c, 0, 0, 0);
}

// Problem constants: B=2, S=2048, DIM=1024, H=16, D=64, B1=B2=8, F=32, ITERS=2
// seq position s = g*64 + i*8 + j ; kv position = f*64 + k*8 + l
// Packed L/R slices: slice(bh,g,f) base = (bh*528 + g(g+1)/2 + f) * 512 elems.
// L slice layout: o = j*64 + k*8 + i ; R slice layout: o = k*64 + j*8 + l.
// stats layout: stats[((bh*32+g)*64 + j*8+i)*2 + {0:max,1:1/sum}]

// ---------------- K1: cast x, wq|wk|wv -> fp16 ----------------
__global__ __launch_bounds__(256) void k_cast(
    const float* __restrict__ x, const float* __restrict__ wq,
    const float* __restrict__ wk, const float* __restrict__ wv,
    f16* __restrict__ xh, f16* __restrict__ wcat) {
  const int64_t nx4 = 4194304 / 4;
  const int64_t nw4 = 1048576 / 4;
  int64_t stride = (int64_t)gridDim.x * blockDim.x;
  for (int64_t i = (int64_t)blockIdx.x * blockDim.x + threadIdx.x;
       i < nx4 + 3 * nw4; i += stride) {
    const float* src; f16* dst; int64_t off;
    if (i < nx4) { src = x; dst = xh; off = i; }
    else {
      int64_t r = i - nx4;
      int ws_ = (int)(r / nw4);
      off = r - (int64_t)ws_ * nw4;
      src = (ws_ == 0) ? wq : ((ws_ == 1) ? wk : wv);
      dst = wcat + (int64_t)ws_ * 1048576;
    }
    float4 v = ((const float4*)src)[off];
    half4v hh; hh[0] = (f16)v.x; hh[1] = (f16)v.y; hh[2] = (f16)v.z; hh[3] = (f16)v.w;
    ((half4v*)dst)[off] = hh;
  }
}

// ---------------- K2: P[4096][3072] = xh[4096][1024] @ wcat[3072][1024]^T ----
__global__ __launch_bounds__(256) void k_gemm(
    const f16* __restrict__ A, const f16* __restrict__ Bm,
    float* __restrict__ P) {
  __shared__ f16 As[128 * 72];
  __shared__ f16 Bs[128 * 72];
  const int t = threadIdx.x;
  const int wave = t >> 6, lane = t & 63, quad = lane >> 4, ln = lane & 15;
  const int tM = blockIdx.x / 24, tN = blockIdx.x % 24;
  const int wm = wave >> 1, wn = wave & 1;
  f32x4 acc[4][4];
#pragma unroll
  for (int a = 0; a < 4; ++a)
#pragma unroll
    for (int b = 0; b < 4; ++b) { f32x4 z = {0.f, 0.f, 0.f, 0.f}; acc[a][b] = z; }
  const int r = t >> 1, hf = t & 1;
  const f16* Ag = A + (int64_t)(tM * 128 + r) * 1024 + hf * 32;
  const f16* Bg = Bm + (int64_t)(tN * 128 + r) * 1024 + hf * 32;
  f16* Asw = &As[r * 72 + hf * 32];
  f16* Bsw = &Bs[r * 72 + hf * 32];
  for (int kt = 0; kt < 16; ++kt) {
    half8 a0 = *(const half8*)(Ag + kt * 64);
    half8 a1 = *(const half8*)(Ag + kt * 64 + 8);
    half8 a2 = *(const half8*)(Ag + kt * 64 + 16);
    half8 a3 = *(const half8*)(Ag + kt * 64 + 24);
    half8 b0 = *(const half8*)(Bg + kt * 64);
    half8 b1 = *(const half8*)(Bg + kt * 64 + 8);
    half8 b2 = *(const half8*)(Bg + kt * 64 + 16);
    half8 b3 = *(const half8*)(Bg + kt * 64 + 24);
    __syncthreads();
    *(half8*)(Asw) = a0; *(half8*)(Asw + 8) = a1;
    *(half8*)(Asw + 16) = a2; *(half8*)(Asw + 24) = a3;
    *(half8*)(Bsw) = b0; *(half8*)(Bsw + 8) = b1;
    *(half8*)(Bsw + 16) = b2; *(half8*)(Bsw + 24) = b3;
    __syncthreads();
#pragma unroll
    for (int ks = 0; ks < 2; ++ks) {
      half8 bf[4];
#pragma unroll
      for (int tn = 0; tn < 4; ++tn)
        bf[tn] = *(const half8*)&Bs[(wn * 64 + tn * 16 + ln) * 72 + ks * 32 + quad * 8];
#pragma unroll
      for (int tm = 0; tm < 4; ++tm) {
        half8 af = *(const half8*)&As[(wm * 64 + tm * 16 + ln) * 72 + ks * 32 + quad * 8];
#pragma unroll
        for (int tn = 0; tn < 4; ++tn)
          acc[tm][tn] = mfma16(af, bf[tn], acc[tm][tn]);
      }
    }
  }
#pragma unroll
  for (int tm = 0; tm < 4; ++tm)
#pragma unroll
    for (int tn = 0; tn < 4; ++tn)
#pragma unroll
      for (int r2 = 0; r2 < 4; ++r2) {
        int row = tM * 128 + wm * 64 + tm * 16 + quad * 4 + r2;
        int col = tN * 128 + wn * 64 + tn * 16 + ln;
        P[(int64_t)row * 3072 + col] = acc[tm][tn][r2];
      }
}

// ---------------- K3: rmsnorm+rope+scale for q,k; v -> transposed fp16 ------
__global__ __launch_bounds__(256) void k_epilogue(
    const float* __restrict__ P, const float* __restrict__ cosg,
    const float* __restrict__ sing, const float* __restrict__ gq,
    const float* __restrict__ gk, f16* __restrict__ qh,
    f16* __restrict__ kh, f16* __restrict__ vth) {
  __shared__ f16 vbuf[64 * 72];
  const int t = threadIdx.x;
  const int bid = blockIdx.x;
  const int st = bid & 31, h = (bid >> 5) & 15, b = bid >> 9;
  const int r = t >> 2, qt = t & 3, c0 = qt * 16;
  const int s = st * 64 + r;
  const int64_t rowbase = (int64_t)(b * 2048 + s) * 3072;
  const float scale = 0.35355339059327373f;  // 64^-0.25
#pragma unroll
  for (int m = 0; m < 2; ++m) {
    const float* gv = (m == 0) ? gq : gk;
    const int colbase = m * 1024 + h * 64 + c0;
    float xv[16];
#pragma unroll
    for (int c = 0; c < 4; ++c) {
      float4 v4 = *(const float4*)&P[rowbase + colbase + c * 4];
      xv[c * 4 + 0] = v4.x; xv[c * 4 + 1] = v4.y;
      xv[c * 4 + 2] = v4.z; xv[c * 4 + 3] = v4.w;
    }
    float ss = 0.f;
#pragma unroll
    for (int c = 0; c < 16; ++c) ss += xv[c] * xv[c];
    ss += __shfl_xor(ss, 1, 64);
    ss += __shfl_xor(ss, 2, 64);
    float rs = rsqrtf(ss * (1.f / 64.f) + 1e-6f);
    alignas(16) f16 res[16];
#pragma unroll
    for (int ci = 0; ci < 16; ci += 2) {
      int d0 = c0 + ci, d1 = d0 + 1;
      float av = xv[ci] * rs * gv[d0];
      float bv = xv[ci + 1] * rs * gv[d1];
      float c0v = cosg[s * 64 + d0], c1v = cosg[s * 64 + d1];
      float s0v = sing[s * 64 + d0], s1v = sing[s * 64 + d1];
      res[ci]     = (f16)((av * c0v - bv * s0v) * scale);
      res[ci + 1] = (f16)((bv * c1v + av * s1v) * scale);
    }
    f16* dst = ((m == 0) ? qh : kh) + (int64_t)((b * 16 + h) * 2048 + s) * 64 + c0;
    *(half8*)dst = *(const half8*)&res[0];
    *(half8*)(dst + 8) = *(const half8*)&res[8];
  }
  {
    const int colbase = 2048 + h * 64 + c0;
#pragma unroll
    for (int c = 0; c < 4; ++c) {
      float4 v4 = *(const float4*)&P[rowbase + colbase + c * 4];
      vbuf[(c0 + c * 4 + 0) * 72 + r] = (f16)v4.x;
      vbuf[(c0 + c * 4 + 1) * 72 + r] = (f16)v4.y;
      vbuf[(c0 + c * 4 + 2) * 72 + r] = (f16)v4.z;
      vbuf[(c0 + c * 4 + 3) * 72 + r] = (f16)v4.w;
    }
    __syncthreads();
    const int d = t >> 2, sc = qt * 16;
    alignas(16) f16 tmp[16];
#pragma unroll
    for (int ci = 0; ci < 16; ++ci) tmp[ci] = vbuf[d * 72 + sc + ci];
    f16* dst = vth + (int64_t)((b * 16 + h) * 64 + d) * 2048 + st * 64 + sc;
    *(half8*)dst = *(const half8*)&tmp[0];
    *(half8*)(dst + 8) = *(const half8*)&tmp[8];
  }
}

// ---------------- K4: phase kernel — ONE WAVE per (bh,g,f) ------------------
// Lane (j,k) owns softmax row: all reductions in-register, zero cross-lane.
// S LDS layout word-index: i*552 + j*68 + k*8 + l
//   scatter writes: exact 2-way banks (free); b128 reads: uniform 8 words/bank.
__global__ __launch_bounds__(64) void k_phase(
    const f16* __restrict__ qh, const f16* __restrict__ kh,
    float* __restrict__ Lg, f16* __restrict__ Rg,
    const float* __restrict__ stats, int iter) {
  __shared__ float Sw[4416];   // 17664 B
  const int lane = threadIdx.x;
  const int quad = lane >> 4, ln = lane & 15;
  const int jr = lane >> 3, kr = lane & 7;   // lane = jr*8 + kr

  const int bh = blockIdx.x / 528;
  const int rem = blockIdx.x - bh * 528;
  int g = (int)((sqrtf(8.f * (float)rem + 1.f) - 1.f) * 0.5f);
  while ((g + 1) * (g + 2) / 2 <= rem) ++g;
  while (g * (g + 1) / 2 > rem) --g;
  const int f = rem - g * (g + 1) / 2;

  const f16* qg = qh + (int64_t)(bh * 2048 + g * 64) * 64;
  const f16* kf = kh + (int64_t)(bh * 2048 + f * 64) * 64;
  const int64_t sbase = ((int64_t)bh * 528 + ((g * (g + 1)) >> 1) + f) * 512;
  float* Lp = Lg + sbase;

  // --- fragments direct from global ---
  half8 afr[2][4], bfr[2][4];
#pragma unroll
  for (int ks = 0; ks < 2; ++ks)
#pragma unroll
    for (int t4 = 0; t4 < 4; ++t4) {
      afr[ks][t4] = *(const half8*)&qg[(t4 * 16 + ln) * 64 + ks * 32 + quad * 8];
      bfr[ks][t4] = *(const half8*)&kf[(t4 * 16 + ln) * 64 + ks * 32 + quad * 8];
    }
  // --- iter2: this lane's L-probs p[i] = softmaxed L[jr,kr,i] ---
  float p[8], cR = 0.f;
  if (iter) {
    float lraw[8];
    *(float4*)&lraw[0] = *(const float4*)&Lp[lane * 8];
    *(float4*)&lraw[4] = *(const float4*)&Lp[lane * 8 + 4];
    const float* stb = &stats[(((size_t)(bh * 32 + g)) * 64 + jr * 8) * 2];
    float st[16];
#pragma unroll
    for (int c = 0; c < 4; ++c) *(float4*)&st[c * 4] = *(const float4*)&stb[c * 4];
#pragma unroll
    for (int i = 0; i < 8; ++i) {
      p[i] = __expf(lraw[i] - st[2 * i]) * st[2 * i + 1];
      cR += p[i];
    }
  }
  // --- S = q_g k_f^T (full 64x64, one wave, 32 MFMA) ---
  f32x4 acc[4][4];
#pragma unroll
  for (int a = 0; a < 4; ++a)
#pragma unroll
    for (int b = 0; b < 4; ++b) { f32x4 z = {0.f, 0.f, 0.f, 0.f}; acc[a][b] = z; }
#pragma unroll
  for (int ks = 0; ks < 2; ++ks)
#pragma unroll
    for (int mt = 0; mt < 4; ++mt)
#pragma unroll
      for (int nt = 0; nt < 4; ++nt)
        acc[mt][nt] = mfma16(afr[ks][mt], bfr[ks][nt], acc[mt][nt]);
  // scatter store: m=mt*16+quad*4+r2 -> (i=m>>3, j=m&7); n=nt*16+ln -> (k,l)
  const int wbase = (quad >> 1) * 552 + (quad & 1) * 272 + (ln >> 3) * 8 + (ln & 7);
#pragma unroll
  for (int mt = 0; mt < 4; ++mt)
#pragma unroll
    for (int nt = 0; nt < 4; ++nt)
#pragma unroll
      for (int r2 = 0; r2 < 4; ++r2)
        Sw[wbase + mt * 1104 + nt * 16 + r2 * 68] = acc[mt][nt][r2];
  __syncthreads();   // single wave: compiles to waitcnt (+cheap barrier)
  // --- pull this lane's S[:,jr,kr,:] block into registers (16 b128) ---
  float Sr[8][8];
  const int rb = jr * 68 + kr * 8;
#pragma unroll
  for (int i = 0; i < 8; ++i) {
    *(float4*)&Sr[i][0] = *(const float4*)&Sw[i * 552 + rb];
    *(float4*)&Sr[i][4] = *(const float4*)&Sw[i * 552 + rb + 4];
  }
  // --- bR -> softmax over l (all in-register) ---
  float va[8];
  if (!iter) {
    // L = block identity: bR[l] = S[(kr,jr),(kr,l)], cR = 1
    float4 d0 = *(const float4*)&Sw[kr * 552 + rb];
    float4 d1 = *(const float4*)&Sw[kr * 552 + rb + 4];
    va[0] = d0.x; va[1] = d0.y; va[2] = d0.z; va[3] = d0.w;
    va[4] = d1.x; va[5] = d1.y; va[6] = d1.z; va[7] = d1.w;
    const float sc = 1.f / (1.f + 1e-6f);
#pragma unroll
    for (int l = 0; l < 8; ++l) va[l] *= sc;
  } else {
    float bR[8];
#pragma unroll
    for (int l = 0; l < 8; ++l) bR[l] = 0.f;
#pragma unroll
    for (int i = 0; i < 8; ++i)
#pragma unroll
      for (int l = 0; l < 8; ++l) bR[l] += p[i] * Sr[i][l];
    const float rc = 1.f / (cR + 1e-6f);
#pragma unroll
    for (int l = 0; l < 8; ++l) va[l] = bR[l] * rc;
  }
  float mx = va[0];
#pragma unroll
  for (int l = 1; l < 8; ++l) mx = fmaxf(mx, va[l]);
  float ex[8], sm = 0.f;
#pragma unroll
  for (int l = 0; l < 8; ++l) { ex[l] = __expf(va[l] - mx); sm += ex[l]; }
  const float inv = 1.f / sm;
  float rr[8], rl = 0.f;
#pragma unroll
  for (int l = 0; l < 8; ++l) {
    rr[l] = ex[l] * inv;
    rl += rr[l] * __logf(fmaxf(rr[l], 1e-30f));
  }
  if (iter) {  // store R row (16B coalesced)
    half8 r8;
#pragma unroll
    for (int l = 0; l < 8; ++l) r8[l] = (f16)rr[l];
    *(half8*)&Rg[sbase + kr * 64 + jr * 8] = r8;
  }
  // --- bL[i] = sum_l rr*S - rl ; overwrite L slice ---
  float bl[8];
#pragma unroll
  for (int i = 0; i < 8; ++i) {
    float s = 0.f;
#pragma unroll
    for (int l = 0; l < 8; ++l) s += rr[l] * Sr[i][l];
    bl[i] = s - rl;
  }
  *(float4*)&Lp[lane * 8]     = *(const float4*)&bl[0];
  *(float4*)&Lp[lane * 8 + 4] = *(const float4*)&bl[4];
}

// ---------------- K5: softmax STATS only (max, 1/sum) per (bh,g,(j,i)) ------
__global__ __launch_bounds__(256) void k_stats(
    const float* __restrict__ Lg, float* __restrict__ stats) {
  __shared__ float Ls[32 * 546];
  const int t = threadIdx.x;
  const int g = 31 - (blockIdx.x & 31), bh = blockIdx.x >> 5;
  const float* Lp = Lg + ((int64_t)bh * 528 + ((g * (g + 1)) >> 1)) * 512;
  for (int f = 0; f <= g; ++f) {
    const int o = 2 * t;
    *(float2*)&Ls[f * 546 + (o >> 6) * 68 + (o & 63)] = *(const float2*)&Lp[f * 512 + o];
  }
  __syncthreads();
  const int p = t >> 2, sub = t & 3;
  const int j = p >> 3, i = p & 7;
  const int base = j * 68 + i;
  float mx = -1e30f;
  for (int f = sub; f <= g; f += 4)
#pragma unroll
    for (int k_ = 0; k_ < 8; ++k_)
      mx = fmaxf(mx, Ls[f * 546 + base + k_ * 8]);
  mx = fmaxf(mx, __shfl_xor(mx, 1, 64));
  mx = fmaxf(mx, __shfl_xor(mx, 2, 64));
  float se = 0.f;
  for (int f = sub; f <= g; f += 4)
#pragma unroll
    for (int k_ = 0; k_ < 8; ++k_)
      se += __expf(Ls[f * 546 + base + k_ * 8] - mx);
  se += __shfl_xor(se, 1, 64);
  se += __shfl_xor(se, 2, 64);
  if (sub == 0) {
    float* st = &stats[((size_t)(bh * 32 + g) * 64 + p) * 2];
    st[0] = mx;
    st[1] = 1.f / se;
  }
}

// ---------------- K6: output pass — barrier-free, waves independent ---------
// wave = d-slice (nt); v/L/R fragments gathered straight from global (L2).
__global__ __launch_bounds__(256) void k_out(
    const float* __restrict__ Lg, const f16* __restrict__ Rg,
    const f16* __restrict__ vth, const float* __restrict__ stats,
    float* __restrict__ out) {
  const int t = threadIdx.x;
  const int wave = t >> 6, lane = t & 63, quad = lane >> 4, ln = lane & 15;
  const int g = 31 - (blockIdx.x & 31), bh = blockIdx.x >> 5;
  const int64_t sbase = ((int64_t)bh * 528 + ((g * (g + 1)) >> 1)) * 512;
  const float* Lp = Lg + sbase;
  const f16* Rp = Rg + sbase;
  const f16* vb = vth + ((int64_t)bh * 64 + wave * 16 + ln) * 2048;
  const int jl = ln & 7;
  float mxs[4], invs[4];
  const float* stb = &stats[((size_t)(bh * 32 + g) * 64) * 2];
#pragma unroll
  for (int mt = 0; mt < 4; ++mt) {
    const int i = mt * 2 + (ln >> 3);
    float2 s2 = *(const float2*)&stb[(jl * 8 + i) * 2];
    mxs[mt] = s2.x; invs[mt] = s2.y;
  }
  f32x4 oacc[4];
#pragma unroll
  for (int mt = 0; mt < 4; ++mt) { f32x4 z = {0.f, 0.f, 0.f, 0.f}; oacc[mt] = z; }
  for (int f = 0; f <= g; ++f) {
    const float* Lf = Lp + f * 512;
    const f16* Rf = Rp + f * 512;
    half8 v8[2];
    v8[0] = *(const half8*)&vb[f * 64 + quad * 8];
    v8[1] = *(const half8*)&vb[f * 64 + 32 + quad * 8];
#pragma unroll
    for (int ks = 0; ks < 2; ++ks) {
      const int k4 = ks * 4 + quad;
      half8 r8[4]; float lraw[4];
#pragma unroll
      for (int mt = 0; mt < 4; ++mt) {
        const int i = mt * 2 + (ln >> 3);
        lraw[mt] = Lf[jl * 64 + k4 * 8 + i];
        r8[mt] = *(const half8*)&Rf[k4 * 64 + jl * 8];
      }
#pragma unroll
      for (int mt = 0; mt < 4; ++mt) {
        const f16 Lh = (f16)(__expf(lraw[mt] - mxs[mt]) * invs[mt]);
        half8 w8;
#pragma unroll
        for (int l = 0; l < 8; ++l) w8[l] = r8[mt][l] * Lh;
        oacc[mt] = mfma16(w8, v8[ks], oacc[mt]);
      }
    }
  }
  float* ob = out + (int64_t)((bh >> 4) * 2048 + g * 64) * 1024 + (bh & 15) * 64;
#pragma unroll
  for (int mt = 0; mt < 4; ++mt)
#pragma unroll
    for (int r2 = 0; r2 < 4; ++r2)
      ob[(int64_t)(mt * 16 + quad * 4 + r2) * 1024 + wave * 16 + ln] = oacc[mt][r2];
}

// ---------------------------------------------------------------------------
extern "C" void kernel_launch(void* const* d_in, const int* in_sizes, int n_in,
                              void* d_out, int out_size, void* d_ws, size_t ws_size,
                              hipStream_t stream) {
  const float* x    = (const float*)d_in[0];
  const float* cosg = (const float*)d_in[1];
  const float* sing = (const float*)d_in[2];
  const float* wq   = (const float*)d_in[3];
  const float* wk   = (const float*)d_in[4];
  const float* wv   = (const float*)d_in[5];
  const float* gq   = (const float*)d_in[6];
  const float* gk   = (const float*)d_in[7];
  float* out = (float*)d_out;

  char* ws = (char*)d_ws;
  f16*   xh     = (f16*)(ws);                     // 8,388,608 B
  f16*   wcat   = (f16*)(ws + 8388608);           // 6,291,456 B
  float* P      = (float*)(ws + 14680064);        // 50,331,648 B (dead after K3)
  f16*   Rg     = (f16*)(ws + 14680064);          // 17,301,504 B (aliases P)
  float* stats1 = (float*)(ws + 31981568);        // 524,288 B
  float* stats2 = (float*)(ws + 32505856);        // 524,288 B
  f16*   qh     = (f16*)(ws + 65011712);          // 8,388,608 B
  f16*   kh     = (f16*)(ws + 73400320);          // 8,388,608 B
  f16*   vth    = (f16*)(ws + 81788928);          // 8,388,608 B
  float* Lg     = (float*)(ws + 90177536);        // 34,603,008 B -> end ~119 MB

  hipLaunchKernelGGL(k_cast, dim3(1024), dim3(256), 0, stream, x, wq, wk, wv, xh, wcat);
  hipLaunchKernelGGL(k_gemm, dim3(768), dim3(256), 0, stream, xh, wcat, P);
  hipLaunchKernelGGL(k_epilogue, dim3(1024), dim3(256), 0, stream,
                     P, cosg, sing, gq, gk, qh, kh, vth);
  hipLaunchKernelGGL(k_phase, dim3(16896), dim3(64), 0, stream, qh, kh, Lg, Rg, stats1, 0);
  hipLaunchKernelGGL(k_stats, dim3(1024), dim3(256), 0, stream, Lg, stats1);
  hipLaunchKernelGGL(k_phase, dim3(16896), dim3(64), 0, stream, qh, kh, Lg, Rg, stats1, 1);
  hipLaunchKernelGGL(k_stats, dim3(1024), dim3(256), 0, stream, Lg, stats2);
  hipLaunchKernelGGL(k_out, dim3(1024), dim3(256), 0, stream, Lg, Rg, vth, stats2, out);
}

// Round 5
// 349.443 us; speedup vs baseline: 2.3382x; 1.0088x over previous
//
#include <hip/hip_runtime.h>
#include <stdint.h>

typedef _Float16 f16;
typedef _Float16 half8 __attribute__((ext_vector_type(8)));
typedef _Float16 half4v __attribute__((ext_vector_type(4)));
typedef float f32x4 __attribute__((ext_vector_type(4)));

#define DEV static __device__ __forceinline__

DEV f32x4 mfma16(half8 a, half8 b, f32x4 c) {
  return __builtin_amdgcn_mfma_f32_16x16x32_f16(a, b, c, 0, 0, 0);
}

// Problem constants: B=2, S=2048, DIM=1024, H=16, D=64, B1=B2=8, F=32, ITERS=2
// seq position s = g*64 + i*8 + j ; kv position = f*64 + k*8 + l
// Packed L/R slices: slice(bh,g,f) base = (bh*528 + g(g+1)/2 + f) * 512 elems.
// L slice layout: o = j*64 + k*8 + i ; R slice layout: o = k*64 + j*8 + l.
// stats layout: stats[((bh*32+g)*64 + j*8+i)*2 + {0:max,1:1/sum}]
// vth layout: [bh][f][d][64] fp16 (f-block compact 8 KB for L2 locality).

// ---------------- K1: cast x, wq|wk|wv -> fp16 ----------------
__global__ __launch_bounds__(256) void k_cast(
    const float* __restrict__ x, const float* __restrict__ wq,
    const float* __restrict__ wk, const float* __restrict__ wv,
    f16* __restrict__ xh, f16* __restrict__ wcat) {
  const int64_t nx4 = 4194304 / 4;
  const int64_t nw4 = 1048576 / 4;
  int64_t stride = (int64_t)gridDim.x * blockDim.x;
  for (int64_t i = (int64_t)blockIdx.x * blockDim.x + threadIdx.x;
       i < nx4 + 3 * nw4; i += stride) {
    const float* src; f16* dst; int64_t off;
    if (i < nx4) { src = x; dst = xh; off = i; }
    else {
      int64_t r = i - nx4;
      int ws_ = (int)(r / nw4);
      off = r - (int64_t)ws_ * nw4;
      src = (ws_ == 0) ? wq : ((ws_ == 1) ? wk : wv);
      dst = wcat + (int64_t)ws_ * 1048576;
    }
    float4 v = ((const float4*)src)[off];
    half4v hh; hh[0] = (f16)v.x; hh[1] = (f16)v.y; hh[2] = (f16)v.z; hh[3] = (f16)v.w;
    ((half4v*)dst)[off] = hh;
  }
}

// ---------------- K2: P[4096][3072] = xh[4096][1024] @ wcat[3072][1024]^T ----
__global__ __launch_bounds__(256) void k_gemm(
    const f16* __restrict__ A, const f16* __restrict__ Bm,
    float* __restrict__ P) {
  __shared__ f16 As[128 * 72];
  __shared__ f16 Bs[128 * 72];
  const int t = threadIdx.x;
  const int wave = t >> 6, lane = t & 63, quad = lane >> 4, ln = lane & 15;
  const int tM = blockIdx.x / 24, tN = blockIdx.x % 24;
  const int wm = wave >> 1, wn = wave & 1;
  f32x4 acc[4][4];
#pragma unroll
  for (int a = 0; a < 4; ++a)
#pragma unroll
    for (int b = 0; b < 4; ++b) { f32x4 z = {0.f, 0.f, 0.f, 0.f}; acc[a][b] = z; }
  const int r = t >> 1, hf = t & 1;
  const f16* Ag = A + (int64_t)(tM * 128 + r) * 1024 + hf * 32;
  const f16* Bg = Bm + (int64_t)(tN * 128 + r) * 1024 + hf * 32;
  f16* Asw = &As[r * 72 + hf * 32];
  f16* Bsw = &Bs[r * 72 + hf * 32];
  for (int kt = 0; kt < 16; ++kt) {
    half8 a0 = *(const half8*)(Ag + kt * 64);
    half8 a1 = *(const half8*)(Ag + kt * 64 + 8);
    half8 a2 = *(const half8*)(Ag + kt * 64 + 16);
    half8 a3 = *(const half8*)(Ag + kt * 64 + 24);
    half8 b0 = *(const half8*)(Bg + kt * 64);
    half8 b1 = *(const half8*)(Bg + kt * 64 + 8);
    half8 b2 = *(const half8*)(Bg + kt * 64 + 16);
    half8 b3 = *(const half8*)(Bg + kt * 64 + 24);
    __syncthreads();
    *(half8*)(Asw) = a0; *(half8*)(Asw + 8) = a1;
    *(half8*)(Asw + 16) = a2; *(half8*)(Asw + 24) = a3;
    *(half8*)(Bsw) = b0; *(half8*)(Bsw + 8) = b1;
    *(half8*)(Bsw + 16) = b2; *(half8*)(Bsw + 24) = b3;
    __syncthreads();
#pragma unroll
    for (int ks = 0; ks < 2; ++ks) {
      half8 bf[4];
#pragma unroll
      for (int tn = 0; tn < 4; ++tn)
        bf[tn] = *(const half8*)&Bs[(wn * 64 + tn * 16 + ln) * 72 + ks * 32 + quad * 8];
#pragma unroll
      for (int tm = 0; tm < 4; ++tm) {
        half8 af = *(const half8*)&As[(wm * 64 + tm * 16 + ln) * 72 + ks * 32 + quad * 8];
#pragma unroll
        for (int tn = 0; tn < 4; ++tn)
          acc[tm][tn] = mfma16(af, bf[tn], acc[tm][tn]);
      }
    }
  }
#pragma unroll
  for (int tm = 0; tm < 4; ++tm)
#pragma unroll
    for (int tn = 0; tn < 4; ++tn)
#pragma unroll
      for (int r2 = 0; r2 < 4; ++r2) {
        int row = tM * 128 + wm * 64 + tm * 16 + quad * 4 + r2;
        int col = tN * 128 + wn * 64 + tn * 16 + ln;
        P[(int64_t)row * 3072 + col] = acc[tm][tn][r2];
      }
}

// ---------------- K3: rmsnorm+rope+scale for q,k; v -> [bh][f][d][64] f16 ---
__global__ __launch_bounds__(256) void k_epilogue(
    const float* __restrict__ P, const float* __restrict__ cosg,
    const float* __restrict__ sing, const float* __restrict__ gq,
    const float* __restrict__ gk, f16* __restrict__ qh,
    f16* __restrict__ kh, f16* __restrict__ vth) {
  __shared__ f16 vbuf[64 * 72];
  const int t = threadIdx.x;
  const int bid = blockIdx.x;
  const int st = bid & 31, h = (bid >> 5) & 15, b = bid >> 9;
  const int r = t >> 2, qt = t & 3, c0 = qt * 16;
  const int s = st * 64 + r;
  const int64_t rowbase = (int64_t)(b * 2048 + s) * 3072;
  const float scale = 0.35355339059327373f;  // 64^-0.25
#pragma unroll
  for (int m = 0; m < 2; ++m) {
    const float* gv = (m == 0) ? gq : gk;
    const int colbase = m * 1024 + h * 64 + c0;
    float xv[16];
#pragma unroll
    for (int c = 0; c < 4; ++c) {
      float4 v4 = *(const float4*)&P[rowbase + colbase + c * 4];
      xv[c * 4 + 0] = v4.x; xv[c * 4 + 1] = v4.y;
      xv[c * 4 + 2] = v4.z; xv[c * 4 + 3] = v4.w;
    }
    float ss = 0.f;
#pragma unroll
    for (int c = 0; c < 16; ++c) ss += xv[c] * xv[c];
    ss += __shfl_xor(ss, 1, 64);
    ss += __shfl_xor(ss, 2, 64);
    float rs = rsqrtf(ss * (1.f / 64.f) + 1e-6f);
    alignas(16) f16 res[16];
#pragma unroll
    for (int ci = 0; ci < 16; ci += 2) {
      int d0 = c0 + ci, d1 = d0 + 1;
      float av = xv[ci] * rs * gv[d0];
      float bv = xv[ci + 1] * rs * gv[d1];
      float c0v = cosg[s * 64 + d0], c1v = cosg[s * 64 + d1];
      float s0v = sing[s * 64 + d0], s1v = sing[s * 64 + d1];
      res[ci]     = (f16)((av * c0v - bv * s0v) * scale);
      res[ci + 1] = (f16)((bv * c1v + av * s1v) * scale);
    }
    f16* dst = ((m == 0) ? qh : kh) + (int64_t)((b * 16 + h) * 2048 + s) * 64 + c0;
    *(half8*)dst = *(const half8*)&res[0];
    *(half8*)(dst + 8) = *(const half8*)&res[8];
  }
  {
    const int colbase = 2048 + h * 64 + c0;
#pragma unroll
    for (int c = 0; c < 4; ++c) {
      float4 v4 = *(const float4*)&P[rowbase + colbase + c * 4];
      vbuf[(c0 + c * 4 + 0) * 72 + r] = (f16)v4.x;
      vbuf[(c0 + c * 4 + 1) * 72 + r] = (f16)v4.y;
      vbuf[(c0 + c * 4 + 2) * 72 + r] = (f16)v4.z;
      vbuf[(c0 + c * 4 + 3) * 72 + r] = (f16)v4.w;
    }
    __syncthreads();
    // vth[bh][f=st][d][64]: wave-row d = t>>2, cols qt*16..
    const int d = t >> 2, sc = qt * 16;
    alignas(16) f16 tmp[16];
#pragma unroll
    for (int ci = 0; ci < 16; ++ci) tmp[ci] = vbuf[d * 72 + sc + ci];
    f16* dst = vth + (int64_t)(((b * 16 + h) * 32 + st) * 64 + d) * 64 + sc;
    *(half8*)dst = *(const half8*)&tmp[0];
    *(half8*)(dst + 8) = *(const half8*)&tmp[8];
  }
}

// ---------------- K4: phase kernel — ONE WAVE per (bh,g,f) ------------------
__global__ __launch_bounds__(64) void k_phase(
    const f16* __restrict__ qh, const f16* __restrict__ kh,
    float* __restrict__ Lg, f16* __restrict__ Rg,
    const float* __restrict__ stats, int iter) {
  __shared__ float Sw[4416];   // 17664 B
  const int lane = threadIdx.x;
  const int quad = lane >> 4, ln = lane & 15;
  const int jr = lane >> 3, kr = lane & 7;   // lane = jr*8 + kr

  const int bh = blockIdx.x / 528;
  const int rem = blockIdx.x - bh * 528;
  int g = (int)((sqrtf(8.f * (float)rem + 1.f) - 1.f) * 0.5f);
  while ((g + 1) * (g + 2) / 2 <= rem) ++g;
  while (g * (g + 1) / 2 > rem) --g;
  const int f = rem - g * (g + 1) / 2;

  const f16* qg = qh + (int64_t)(bh * 2048 + g * 64) * 64;
  const f16* kf = kh + (int64_t)(bh * 2048 + f * 64) * 64;
  const int64_t sbase = ((int64_t)bh * 528 + ((g * (g + 1)) >> 1) + f) * 512;
  float* Lp = Lg + sbase;

  half8 afr[2][4], bfr[2][4];
#pragma unroll
  for (int ks = 0; ks < 2; ++ks)
#pragma unroll
    for (int t4 = 0; t4 < 4; ++t4) {
      afr[ks][t4] = *(const half8*)&qg[(t4 * 16 + ln) * 64 + ks * 32 + quad * 8];
      bfr[ks][t4] = *(const half8*)&kf[(t4 * 16 + ln) * 64 + ks * 32 + quad * 8];
    }
  float p[8], cR = 0.f;
  if (iter) {
    float lraw[8];
    *(float4*)&lraw[0] = *(const float4*)&Lp[lane * 8];
    *(float4*)&lraw[4] = *(const float4*)&Lp[lane * 8 + 4];
    const float* stb = &stats[(((size_t)(bh * 32 + g)) * 64 + jr * 8) * 2];
    float st[16];
#pragma unroll
    for (int c = 0; c < 4; ++c) *(float4*)&st[c * 4] = *(const float4*)&stb[c * 4];
#pragma unroll
    for (int i = 0; i < 8; ++i) {
      p[i] = __expf(lraw[i] - st[2 * i]) * st[2 * i + 1];
      cR += p[i];
    }
  }
  f32x4 acc[4][4];
#pragma unroll
  for (int a = 0; a < 4; ++a)
#pragma unroll
    for (int b = 0; b < 4; ++b) { f32x4 z = {0.f, 0.f, 0.f, 0.f}; acc[a][b] = z; }
#pragma unroll
  for (int ks = 0; ks < 2; ++ks)
#pragma unroll
    for (int mt = 0; mt < 4; ++mt)
#pragma unroll
      for (int nt = 0; nt < 4; ++nt)
        acc[mt][nt] = mfma16(afr[ks][mt], bfr[ks][nt], acc[mt][nt]);
  const int wbase = (quad >> 1) * 552 + (quad & 1) * 272 + (ln >> 3) * 8 + (ln & 7);
#pragma unroll
  for (int mt = 0; mt < 4; ++mt)
#pragma unroll
    for (int nt = 0; nt < 4; ++nt)
#pragma unroll
      for (int r2 = 0; r2 < 4; ++r2)
        Sw[wbase + mt * 1104 + nt * 16 + r2 * 68] = acc[mt][nt][r2];
  __syncthreads();
  float Sr[8][8];
  const int rb = jr * 68 + kr * 8;
#pragma unroll
  for (int i = 0; i < 8; ++i) {
    *(float4*)&Sr[i][0] = *(const float4*)&Sw[i * 552 + rb];
    *(float4*)&Sr[i][4] = *(const float4*)&Sw[i * 552 + rb + 4];
  }
  float va[8];
  if (!iter) {
    float4 d0 = *(const float4*)&Sw[kr * 552 + rb];
    float4 d1 = *(const float4*)&Sw[kr * 552 + rb + 4];
    va[0] = d0.x; va[1] = d0.y; va[2] = d0.z; va[3] = d0.w;
    va[4] = d1.x; va[5] = d1.y; va[6] = d1.z; va[7] = d1.w;
    const float sc = 1.f / (1.f + 1e-6f);
#pragma unroll
    for (int l = 0; l < 8; ++l) va[l] *= sc;
  } else {
    float bR[8];
#pragma unroll
    for (int l = 0; l < 8; ++l) bR[l] = 0.f;
#pragma unroll
    for (int i = 0; i < 8; ++i)
#pragma unroll
      for (int l = 0; l < 8; ++l) bR[l] += p[i] * Sr[i][l];
    const float rc = 1.f / (cR + 1e-6f);
#pragma unroll
    for (int l = 0; l < 8; ++l) va[l] = bR[l] * rc;
  }
  float mx = va[0];
#pragma unroll
  for (int l = 1; l < 8; ++l) mx = fmaxf(mx, va[l]);
  float ex[8], sm = 0.f;
#pragma unroll
  for (int l = 0; l < 8; ++l) { ex[l] = __expf(va[l] - mx); sm += ex[l]; }
  const float inv = 1.f / sm;
  float rr[8], rl = 0.f;
#pragma unroll
  for (int l = 0; l < 8; ++l) {
    rr[l] = ex[l] * inv;
    rl += rr[l] * __logf(fmaxf(rr[l], 1e-30f));
  }
  if (iter) {
    half8 r8;
#pragma unroll
    for (int l = 0; l < 8; ++l) r8[l] = (f16)rr[l];
    *(half8*)&Rg[sbase + kr * 64 + jr * 8] = r8;
  }
  float bl[8];
#pragma unroll
  for (int i = 0; i < 8; ++i) {
    float s = 0.f;
#pragma unroll
    for (int l = 0; l < 8; ++l) s += rr[l] * Sr[i][l];
    bl[i] = s - rl;
  }
  *(float4*)&Lp[lane * 8]     = *(const float4*)&bl[0];
  *(float4*)&Lp[lane * 8 + 4] = *(const float4*)&bl[4];
}

// ---------------- K5: softmax STATS only (max, 1/sum) per (bh,g,(j,i)) ------
__global__ __launch_bounds__(256) void k_stats(
    const float* __restrict__ Lg, float* __restrict__ stats) {
  __shared__ float Ls[32 * 546];
  const int t = threadIdx.x;
  const int g = 31 - (blockIdx.x & 31), bh = blockIdx.x >> 5;
  const float* Lp = Lg + ((int64_t)bh * 528 + ((g * (g + 1)) >> 1)) * 512;
  for (int f = 0; f <= g; ++f) {
    const int o = 2 * t;
    *(float2*)&Ls[f * 546 + (o >> 6) * 68 + (o & 63)] = *(const float2*)&Lp[f * 512 + o];
  }
  __syncthreads();
  const int p = t >> 2, sub = t & 3;
  const int j = p >> 3, i = p & 7;
  const int base = j * 68 + i;
  float mx = -1e30f;
  for (int f = sub; f <= g; f += 4)
#pragma unroll
    for (int k_ = 0; k_ < 8; ++k_)
      mx = fmaxf(mx, Ls[f * 546 + base + k_ * 8]);
  mx = fmaxf(mx, __shfl_xor(mx, 1, 64));
  mx = fmaxf(mx, __shfl_xor(mx, 2, 64));
  float se = 0.f;
  for (int f = sub; f <= g; f += 4)
#pragma unroll
    for (int k_ = 0; k_ < 8; ++k_)
      se += __expf(Ls[f * 546 + base + k_ * 8] - mx);
  se += __shfl_xor(se, 1, 64);
  se += __shfl_xor(se, 2, 64);
  if (sub == 0) {
    float* st = &stats[((size_t)(bh * 32 + g) * 64 + p) * 2];
    st[0] = mx;
    st[1] = 1.f / se;
  }
}

// ---------------- K6: output — 2-way f-split + software-pipelined loads -----
// 512 thr = {fg 0,1} x {4 d-slices}; fg handles f ≡ fg (mod 2).
// LDS reduction of the two partials; one barrier total.
__global__ __launch_bounds__(512) void k_out(
    const float* __restrict__ Lg, const f16* __restrict__ Rg,
    const f16* __restrict__ vth, const float* __restrict__ stats,
    float* __restrict__ out) {
  __shared__ float red[64 * 64];   // 16 KB  [idx 0..63][lane]
  const int t = threadIdx.x;
  const int wave = t >> 6, lane = t & 63, quad = lane >> 4, ln = lane & 15;
  const int fg = wave >> 2, dw = wave & 3;
  const int g = 31 - (blockIdx.x & 31), bh = blockIdx.x >> 5;
  const int64_t sbase = ((int64_t)bh * 528 + ((g * (g + 1)) >> 1)) * 512;
  const float* Lp = Lg + sbase;
  const f16* Rp = Rg + sbase;
  // vth[bh][f][d][64]; this lane's row d = dw*16+ln
  const f16* vb = vth + ((int64_t)bh * 32 * 64 + dw * 16 + ln) * 64;
  const int jl = ln & 7, ih = ln >> 3;
  float mxs[4], invs[4];
  const float* stb = &stats[((size_t)(bh * 32 + g) * 64) * 2];
#pragma unroll
  for (int mt = 0; mt < 4; ++mt) {
    float2 s2 = *(const float2*)&stb[(jl * 8 + mt * 2 + ih) * 2];
    mxs[mt] = s2.x; invs[mt] = s2.y;
  }
  f32x4 oacc[4];
#pragma unroll
  for (int mt = 0; mt < 4; ++mt) { f32x4 z = {0.f, 0.f, 0.f, 0.f}; oacc[mt] = z; }

  half8 vA0, vA1, rA0, rA1; float lA[8];
  half8 vB0, vB1, rB0, rB1; float lB[8];
  auto loadit = [&](int f, half8& v0, half8& v1, half8& r0, half8& r1, float* la) {
    const float* Lf = Lp + f * 512;
    const f16* Rf = Rp + f * 512;
    const f16* vf = vb + (int64_t)f * 64 * 64;
    v0 = *(const half8*)&vf[quad * 8];
    v1 = *(const half8*)&vf[32 + quad * 8];
    r0 = *(const half8*)&Rf[quad * 64 + jl * 8];
    r1 = *(const half8*)&Rf[(4 + quad) * 64 + jl * 8];
#pragma unroll
    for (int mt = 0; mt < 4; ++mt) {
      la[mt]     = Lf[jl * 64 + quad * 8 + mt * 2 + ih];
      la[4 + mt] = Lf[jl * 64 + (4 + quad) * 8 + mt * 2 + ih];
    }
  };
  auto compit = [&](half8& v0, half8& v1, half8& r0, half8& r1, float* la) {
#pragma unroll
    for (int mt = 0; mt < 4; ++mt) {
      f16 Lh0 = (f16)(__expf(la[mt] - mxs[mt]) * invs[mt]);
      f16 Lh1 = (f16)(__expf(la[4 + mt] - mxs[mt]) * invs[mt]);
      half8 w0, w1;
#pragma unroll
      for (int l = 0; l < 8; ++l) { w0[l] = r0[l] * Lh0; w1[l] = r1[l] * Lh1; }
      oacc[mt] = mfma16(w0, v0, oacc[mt]);
      oacc[mt] = mfma16(w1, v1, oacc[mt]);
    }
  };
  int f = fg;
  if (f <= g) {
    loadit(f, vA0, vA1, rA0, rA1, lA);
    while (true) {
      if (f + 2 <= g) {
        loadit(f + 2, vB0, vB1, rB0, rB1, lB);
        compit(vA0, vA1, rA0, rA1, lA);
        f += 2;
      } else { compit(vA0, vA1, rA0, rA1, lA); break; }
      if (f + 2 <= g) {
        loadit(f + 2, vA0, vA1, rA0, rA1, lA);
        compit(vB0, vB1, rB0, rB1, lB);
        f += 2;
      } else { compit(vB0, vB1, rB0, rB1, lB); break; }
    }
  }
  // merge fg=1 partial into fg=0 via LDS (stride-1 across lanes: conflict-free)
  if (fg == 1) {
#pragma unroll
    for (int mt = 0; mt < 4; ++mt)
#pragma unroll
      for (int r2 = 0; r2 < 4; ++r2)
        red[(dw * 16 + mt * 4 + r2) * 64 + lane] = oacc[mt][r2];
  }
  __syncthreads();
  if (fg == 0) {
#pragma unroll
    for (int mt = 0; mt < 4; ++mt)
#pragma unroll
      for (int r2 = 0; r2 < 4; ++r2)
        oacc[mt][r2] += red[(dw * 16 + mt * 4 + r2) * 64 + lane];
    float* ob = out + (int64_t)((bh >> 4) * 2048 + g * 64) * 1024 + (bh & 15) * 64;
#pragma unroll
    for (int mt = 0; mt < 4; ++mt)
#pragma unroll
      for (int r2 = 0; r2 < 4; ++r2)
        ob[(int64_t)(mt * 16 + quad * 4 + r2) * 1024 + dw * 16 + ln] = oacc[mt][r2];
  }
}

// ---------------------------------------------------------------------------
extern "C" void kernel_launch(void* const* d_in, const int* in_sizes, int n_in,
                              void* d_out, int out_size, void* d_ws, size_t ws_size,
                              hipStream_t stream) {
  const float* x    = (const float*)d_in[0];
  const float* cosg = (const float*)d_in[1];
  const float* sing = (const float*)d_in[2];
  const float* wq   = (const float*)d_in[3];
  const float* wk   = (const float*)d_in[4];
  const float* wv   = (const float*)d_in[5];
  const float* gq   = (const float*)d_in[6];
  const float* gk   = (const float*)d_in[7];
  float* out = (float*)d_out;

  char* ws = (char*)d_ws;
  f16*   xh     = (f16*)(ws);                     // 8,388,608 B
  f16*   wcat   = (f16*)(ws + 8388608);           // 6,291,456 B
  float* P      = (float*)(ws + 14680064);        // 50,331,648 B (dead after K3)
  f16*   Rg     = (f16*)(ws + 14680064);          // 17,301,504 B (aliases P)
  float* stats1 = (float*)(ws + 31981568);        // 524,288 B
  float* stats2 = (float*)(ws + 32505856);        // 524,288 B
  f16*   qh     = (f16*)(ws + 65011712);          // 8,388,608 B
  f16*   kh     = (f16*)(ws + 73400320);          // 8,388,608 B
  f16*   vth    = (f16*)(ws + 81788928);          // 8,388,608 B
  float* Lg     = (float*)(ws + 90177536);        // 34,603,008 B -> end ~119 MB

  hipLaunchKernelGGL(k_cast, dim3(1024), dim3(256), 0, stream, x, wq, wk, wv, xh, wcat);
  hipLaunchKernelGGL(k_gemm, dim3(768), dim3(256), 0, stream, xh, wcat, P);
  hipLaunchKernelGGL(k_epilogue, dim3(1024), dim3(256), 0, stream,
                     P, cosg, sing, gq, gk, qh, kh, vth);
  hipLaunchKernelGGL(k_phase, dim3(16896), dim3(64), 0, stream, qh, kh, Lg, Rg, stats1, 0);
  hipLaunchKernelGGL(k_stats, dim3(1024), dim3(256), 0, stream, Lg, stats1);
  hipLaunchKernelGGL(k_phase, dim3(16896), dim3(64), 0, stream, qh, kh, Lg, Rg, stats1, 1);
  hipLaunchKernelGGL(k_stats, dim3(1024), dim3(256), 0, stream, Lg, stats2);
  hipLaunchKernelGGL(k_out, dim3(1024), dim3(512), 0, stream, Lg, Rg, vth, stats2, out);
}

// Round 6
// 309.942 us; speedup vs baseline: 2.6362x; 1.1274x over previous
//
#include <hip/hip_runtime.h>
#include <stdint.h>

typedef _Float16 f16;
typedef _Float16 half8 __attribute__((ext_vector_type(8)));
typedef _Float16 half4v __attribute__((ext_vector_type(4)));
typedef float f32x4 __attribute__((ext_vector_type(4)));

#define DEV static __device__ __forceinline__

DEV f32x4 mfma16(half8 a, half8 b, f32x4 c) {
  return __builtin_amdgcn_mfma_f32_16x16x32_f16(a, b, c, 0, 0, 0);
}

// Problem constants: B=2, S=2048, DIM=1024, H=16, D=64, B1=B2=8, F=32, ITERS=2
// seq position s = g*64 + i*8 + j ; kv position = f*64 + k*8 + l
// Packed L/R slices: slice(bh,g,f) base = (bh*528 + g(g+1)/2 + f) * 512 elems.
// L slice layout: o = j*64 + k*8 + i ; R slice layout: o = k*64 + j*8 + l.
// stats layout: stats[((bh*32+g)*64 + j*8+i)*2 + {0:max,1:1/sum}]
// vth layout: [bh][f][d][64] fp16 (f-block compact 8 KB for L2 locality).

// ---------------- K1: cast x, wq|wk|wv -> fp16 ----------------
__global__ __launch_bounds__(256) void k_cast(
    const float* __restrict__ x, const float* __restrict__ wq,
    const float* __restrict__ wk, const float* __restrict__ wv,
    f16* __restrict__ xh, f16* __restrict__ wcat) {
  const int64_t nx4 = 4194304 / 4;
  const int64_t nw4 = 1048576 / 4;
  int64_t stride = (int64_t)gridDim.x * blockDim.x;
  for (int64_t i = (int64_t)blockIdx.x * blockDim.x + threadIdx.x;
       i < nx4 + 3 * nw4; i += stride) {
    const float* src; f16* dst; int64_t off;
    if (i < nx4) { src = x; dst = xh; off = i; }
    else {
      int64_t r = i - nx4;
      int ws_ = (int)(r / nw4);
      off = r - (int64_t)ws_ * nw4;
      src = (ws_ == 0) ? wq : ((ws_ == 1) ? wk : wv);
      dst = wcat + (int64_t)ws_ * 1048576;
    }
    float4 v = ((const float4*)src)[off];
    half4v hh; hh[0] = (f16)v.x; hh[1] = (f16)v.y; hh[2] = (f16)v.z; hh[3] = (f16)v.w;
    ((half4v*)dst)[off] = hh;
  }
}

// ---------------- K2: P[4096][3072] = xh[4096][1024] @ wcat[3072][1024]^T ----
__global__ __launch_bounds__(256) void k_gemm(
    const f16* __restrict__ A, const f16* __restrict__ Bm,
    float* __restrict__ P) {
  __shared__ f16 As[128 * 72];
  __shared__ f16 Bs[128 * 72];
  const int t = threadIdx.x;
  const int wave = t >> 6, lane = t & 63, quad = lane >> 4, ln = lane & 15;
  const int tM = blockIdx.x / 24, tN = blockIdx.x % 24;
  const int wm = wave >> 1, wn = wave & 1;
  f32x4 acc[4][4];
#pragma unroll
  for (int a = 0; a < 4; ++a)
#pragma unroll
    for (int b = 0; b < 4; ++b) { f32x4 z = {0.f, 0.f, 0.f, 0.f}; acc[a][b] = z; }
  const int r = t >> 1, hf = t & 1;
  const f16* Ag = A + (int64_t)(tM * 128 + r) * 1024 + hf * 32;
  const f16* Bg = Bm + (int64_t)(tN * 128 + r) * 1024 + hf * 32;
  f16* Asw = &As[r * 72 + hf * 32];
  f16* Bsw = &Bs[r * 72 + hf * 32];
  for (int kt = 0; kt < 16; ++kt) {
    half8 a0 = *(const half8*)(Ag + kt * 64);
    half8 a1 = *(const half8*)(Ag + kt * 64 + 8);
    half8 a2 = *(const half8*)(Ag + kt * 64 + 16);
    half8 a3 = *(const half8*)(Ag + kt * 64 + 24);
    half8 b0 = *(const half8*)(Bg + kt * 64);
    half8 b1 = *(const half8*)(Bg + kt * 64 + 8);
    half8 b2 = *(const half8*)(Bg + kt * 64 + 16);
    half8 b3 = *(const half8*)(Bg + kt * 64 + 24);
    __syncthreads();
    *(half8*)(Asw) = a0; *(half8*)(Asw + 8) = a1;
    *(half8*)(Asw + 16) = a2; *(half8*)(Asw + 24) = a3;
    *(half8*)(Bsw) = b0; *(half8*)(Bsw + 8) = b1;
    *(half8*)(Bsw + 16) = b2; *(half8*)(Bsw + 24) = b3;
    __syncthreads();
#pragma unroll
    for (int ks = 0; ks < 2; ++ks) {
      half8 bf[4];
#pragma unroll
      for (int tn = 0; tn < 4; ++tn)
        bf[tn] = *(const half8*)&Bs[(wn * 64 + tn * 16 + ln) * 72 + ks * 32 + quad * 8];
#pragma unroll
      for (int tm = 0; tm < 4; ++tm) {
        half8 af = *(const half8*)&As[(wm * 64 + tm * 16 + ln) * 72 + ks * 32 + quad * 8];
#pragma unroll
        for (int tn = 0; tn < 4; ++tn)
          acc[tm][tn] = mfma16(af, bf[tn], acc[tm][tn]);
      }
    }
  }
#pragma unroll
  for (int tm = 0; tm < 4; ++tm)
#pragma unroll
    for (int tn = 0; tn < 4; ++tn)
#pragma unroll
      for (int r2 = 0; r2 < 4; ++r2) {
        int row = tM * 128 + wm * 64 + tm * 16 + quad * 4 + r2;
        int col = tN * 128 + wn * 64 + tn * 16 + ln;
        P[(int64_t)row * 3072 + col] = acc[tm][tn][r2];
      }
}

// ---------------- K3: rmsnorm+rope+scale for q,k; v -> [bh][f][d][64] f16 ---
__global__ __launch_bounds__(256) void k_epilogue(
    const float* __restrict__ P, const float* __restrict__ cosg,
    const float* __restrict__ sing, const float* __restrict__ gq,
    const float* __restrict__ gk, f16* __restrict__ qh,
    f16* __restrict__ kh, f16* __restrict__ vth) {
  __shared__ f16 vbuf[64 * 72];
  const int t = threadIdx.x;
  const int bid = blockIdx.x;
  const int st = bid & 31, h = (bid >> 5) & 15, b = bid >> 9;
  const int r = t >> 2, qt = t & 3, c0 = qt * 16;
  const int s = st * 64 + r;
  const int64_t rowbase = (int64_t)(b * 2048 + s) * 3072;
  const float scale = 0.35355339059327373f;  // 64^-0.25
#pragma unroll
  for (int m = 0; m < 2; ++m) {
    const float* gv = (m == 0) ? gq : gk;
    const int colbase = m * 1024 + h * 64 + c0;
    float xv[16];
#pragma unroll
    for (int c = 0; c < 4; ++c) {
      float4 v4 = *(const float4*)&P[rowbase + colbase + c * 4];
      xv[c * 4 + 0] = v4.x; xv[c * 4 + 1] = v4.y;
      xv[c * 4 + 2] = v4.z; xv[c * 4 + 3] = v4.w;
    }
    float ss = 0.f;
#pragma unroll
    for (int c = 0; c < 16; ++c) ss += xv[c] * xv[c];
    ss += __shfl_xor(ss, 1, 64);
    ss += __shfl_xor(ss, 2, 64);
    float rs = rsqrtf(ss * (1.f / 64.f) + 1e-6f);
    alignas(16) f16 res[16];
#pragma unroll
    for (int ci = 0; ci < 16; ci += 2) {
      int d0 = c0 + ci, d1 = d0 + 1;
      float av = xv[ci] * rs * gv[d0];
      float bv = xv[ci + 1] * rs * gv[d1];
      float c0v = cosg[s * 64 + d0], c1v = cosg[s * 64 + d1];
      float s0v = sing[s * 64 + d0], s1v = sing[s * 64 + d1];
      res[ci]     = (f16)((av * c0v - bv * s0v) * scale);
      res[ci + 1] = (f16)((bv * c1v + av * s1v) * scale);
    }
    f16* dst = ((m == 0) ? qh : kh) + (int64_t)((b * 16 + h) * 2048 + s) * 64 + c0;
    *(half8*)dst = *(const half8*)&res[0];
    *(half8*)(dst + 8) = *(const half8*)&res[8];
  }
  {
    const int colbase = 2048 + h * 64 + c0;
#pragma unroll
    for (int c = 0; c < 4; ++c) {
      float4 v4 = *(const float4*)&P[rowbase + colbase + c * 4];
      vbuf[(c0 + c * 4 + 0) * 72 + r] = (f16)v4.x;
      vbuf[(c0 + c * 4 + 1) * 72 + r] = (f16)v4.y;
      vbuf[(c0 + c * 4 + 2) * 72 + r] = (f16)v4.z;
      vbuf[(c0 + c * 4 + 3) * 72 + r] = (f16)v4.w;
    }
    __syncthreads();
    const int d = t >> 2, sc = qt * 16;
    alignas(16) f16 tmp[16];
#pragma unroll
    for (int ci = 0; ci < 16; ++ci) tmp[ci] = vbuf[d * 72 + sc + ci];
    f16* dst = vth + (int64_t)(((b * 16 + h) * 32 + st) * 64 + d) * 64 + sc;
    *(half8*)dst = *(const half8*)&tmp[0];
    *(half8*)(dst + 8) = *(const half8*)&tmp[8];
  }
}

// ---------------- K4: phase kernel — ONE WAVE per (bh,g,f) ------------------
__global__ __launch_bounds__(64) void k_phase(
    const f16* __restrict__ qh, const f16* __restrict__ kh,
    float* __restrict__ Lg, f16* __restrict__ Rg,
    const float* __restrict__ stats, int iter) {
  __shared__ float Sw[4416];   // 17664 B
  const int lane = threadIdx.x;
  const int quad = lane >> 4, ln = lane & 15;
  const int jr = lane >> 3, kr = lane & 7;   // lane = jr*8 + kr

  const int bh = blockIdx.x / 528;
  const int rem = blockIdx.x - bh * 528;
  int g = (int)((sqrtf(8.f * (float)rem + 1.f) - 1.f) * 0.5f);
  while ((g + 1) * (g + 2) / 2 <= rem) ++g;
  while (g * (g + 1) / 2 > rem) --g;
  const int f = rem - g * (g + 1) / 2;

  const f16* qg = qh + (int64_t)(bh * 2048 + g * 64) * 64;
  const f16* kf = kh + (int64_t)(bh * 2048 + f * 64) * 64;
  const int64_t sbase = ((int64_t)bh * 528 + ((g * (g + 1)) >> 1) + f) * 512;
  float* Lp = Lg + sbase;

  half8 afr[2][4], bfr[2][4];
#pragma unroll
  for (int ks = 0; ks < 2; ++ks)
#pragma unroll
    for (int t4 = 0; t4 < 4; ++t4) {
      afr[ks][t4] = *(const half8*)&qg[(t4 * 16 + ln) * 64 + ks * 32 + quad * 8];
      bfr[ks][t4] = *(const half8*)&kf[(t4 * 16 + ln) * 64 + ks * 32 + quad * 8];
    }
  float p[8], cR = 0.f;
  if (iter) {
    float lraw[8];
    *(float4*)&lraw[0] = *(const float4*)&Lp[lane * 8];
    *(float4*)&lraw[4] = *(const float4*)&Lp[lane * 8 + 4];
    const float* stb = &stats[(((size_t)(bh * 32 + g)) * 64 + jr * 8) * 2];
    float st[16];
#pragma unroll
    for (int c = 0; c < 4; ++c) *(float4*)&st[c * 4] = *(const float4*)&stb[c * 4];
#pragma unroll
    for (int i = 0; i < 8; ++i) {
      p[i] = __expf(lraw[i] - st[2 * i]) * st[2 * i + 1];
      cR += p[i];
    }
  }
  f32x4 acc[4][4];
#pragma unroll
  for (int a = 0; a < 4; ++a)
#pragma unroll
    for (int b = 0; b < 4; ++b) { f32x4 z = {0.f, 0.f, 0.f, 0.f}; acc[a][b] = z; }
#pragma unroll
  for (int ks = 0; ks < 2; ++ks)
#pragma unroll
    for (int mt = 0; mt < 4; ++mt)
#pragma unroll
      for (int nt = 0; nt < 4; ++nt)
        acc[mt][nt] = mfma16(afr[ks][mt], bfr[ks][nt], acc[mt][nt]);
  const int wbase = (quad >> 1) * 552 + (quad & 1) * 272 + (ln >> 3) * 8 + (ln & 7);
#pragma unroll
  for (int mt = 0; mt < 4; ++mt)
#pragma unroll
    for (int nt = 0; nt < 4; ++nt)
#pragma unroll
      for (int r2 = 0; r2 < 4; ++r2)
        Sw[wbase + mt * 1104 + nt * 16 + r2 * 68] = acc[mt][nt][r2];
  __syncthreads();
  float Sr[8][8];
  const int rb = jr * 68 + kr * 8;
#pragma unroll
  for (int i = 0; i < 8; ++i) {
    *(float4*)&Sr[i][0] = *(const float4*)&Sw[i * 552 + rb];
    *(float4*)&Sr[i][4] = *(const float4*)&Sw[i * 552 + rb + 4];
  }
  float va[8];
  if (!iter) {
    float4 d0 = *(const float4*)&Sw[kr * 552 + rb];
    float4 d1 = *(const float4*)&Sw[kr * 552 + rb + 4];
    va[0] = d0.x; va[1] = d0.y; va[2] = d0.z; va[3] = d0.w;
    va[4] = d1.x; va[5] = d1.y; va[6] = d1.z; va[7] = d1.w;
    const float sc = 1.f / (1.f + 1e-6f);
#pragma unroll
    for (int l = 0; l < 8; ++l) va[l] *= sc;
  } else {
    float bR[8];
#pragma unroll
    for (int l = 0; l < 8; ++l) bR[l] = 0.f;
#pragma unroll
    for (int i = 0; i < 8; ++i)
#pragma unroll
      for (int l = 0; l < 8; ++l) bR[l] += p[i] * Sr[i][l];
    const float rc = 1.f / (cR + 1e-6f);
#pragma unroll
    for (int l = 0; l < 8; ++l) va[l] = bR[l] * rc;
  }
  float mx = va[0];
#pragma unroll
  for (int l = 1; l < 8; ++l) mx = fmaxf(mx, va[l]);
  float ex[8], sm = 0.f;
#pragma unroll
  for (int l = 0; l < 8; ++l) { ex[l] = __expf(va[l] - mx); sm += ex[l]; }
  const float inv = 1.f / sm;
  float rr[8], rl = 0.f;
#pragma unroll
  for (int l = 0; l < 8; ++l) {
    rr[l] = ex[l] * inv;
    rl += rr[l] * __logf(fmaxf(rr[l], 1e-30f));
  }
  if (iter) {
    half8 r8;
#pragma unroll
    for (int l = 0; l < 8; ++l) r8[l] = (f16)rr[l];
    *(half8*)&Rg[sbase + kr * 64 + jr * 8] = r8;
  }
  float bl[8];
#pragma unroll
  for (int i = 0; i < 8; ++i) {
    float s = 0.f;
#pragma unroll
    for (int l = 0; l < 8; ++l) s += rr[l] * Sr[i][l];
    bl[i] = s - rl;
  }
  *(float4*)&Lp[lane * 8]     = *(const float4*)&bl[0];
  *(float4*)&Lp[lane * 8 + 4] = *(const float4*)&bl[4];
}

// ---------------- K5: softmax STATS only (max, 1/sum) per (bh,g,(j,i)) ------
__global__ __launch_bounds__(256) void k_stats(
    const float* __restrict__ Lg, float* __restrict__ stats) {
  __shared__ float Ls[32 * 546];
  const int t = threadIdx.x;
  const int g = 31 - (blockIdx.x & 31), bh = blockIdx.x >> 5;
  const float* Lp = Lg + ((int64_t)bh * 528 + ((g * (g + 1)) >> 1)) * 512;
  for (int f = 0; f <= g; ++f) {
    const int o = 2 * t;
    *(float2*)&Ls[f * 546 + (o >> 6) * 68 + (o & 63)] = *(const float2*)&Lp[f * 512 + o];
  }
  __syncthreads();
  const int p = t >> 2, sub = t & 3;
  const int j = p >> 3, i = p & 7;
  const int base = j * 68 + i;
  float mx = -1e30f;
  for (int f = sub; f <= g; f += 4)
#pragma unroll
    for (int k_ = 0; k_ < 8; ++k_)
      mx = fmaxf(mx, Ls[f * 546 + base + k_ * 8]);
  mx = fmaxf(mx, __shfl_xor(mx, 1, 64));
  mx = fmaxf(mx, __shfl_xor(mx, 2, 64));
  float se = 0.f;
  for (int f = sub; f <= g; f += 4)
#pragma unroll
    for (int k_ = 0; k_ < 8; ++k_)
      se += __expf(Ls[f * 546 + base + k_ * 8] - mx);
  se += __shfl_xor(se, 1, 64);
  se += __shfl_xor(se, 2, 64);
  if (sub == 0) {
    float* st = &stats[((size_t)(bh * 32 + g) * 64 + p) * 2];
    st[0] = mx;
    st[1] = 1.f / se;
  }
}

// ---------------- K6: output — g-PAIRED for uniform work --------------------
// Block (bh,G) handles g2=31-G then g1=G: exactly 33 f-units per block.
// 512 thr = {fg 0,1} x {4 d-waves}; fg handles f ≡ fg (mod 2).
__global__ __launch_bounds__(512) void k_out(
    const float* __restrict__ Lg, const f16* __restrict__ Rg,
    const f16* __restrict__ vth, const float* __restrict__ stats,
    float* __restrict__ out) {
  __shared__ float red[64 * 64];   // 16 KB  [idx 0..63][lane]
  const int t = threadIdx.x;
  const int wave = t >> 6, lane = t & 63, quad = lane >> 4, ln = lane & 15;
  const int fg = wave >> 2, dw = wave & 3;
  const int bh = blockIdx.x >> 4, G = blockIdx.x & 15;
  const int jl = ln & 7, ih = ln >> 3;
  // vth[bh][f][d][64]; this lane's row d = dw*16+ln
  const f16* vb = vth + ((int64_t)bh * 32 * 64 + dw * 16 + ln) * 64;

#pragma unroll 1
  for (int ph = 0; ph < 2; ++ph) {
    const int g = ph ? G : 31 - G;
    const int64_t sbase = ((int64_t)bh * 528 + ((g * (g + 1)) >> 1)) * 512;
    const float* Lp = Lg + sbase;
    const f16* Rp = Rg + sbase;
    float mxs[4], invs[4];
    const float* stb = &stats[((size_t)(bh * 32 + g) * 64) * 2];
#pragma unroll
    for (int mt = 0; mt < 4; ++mt) {
      float2 s2 = *(const float2*)&stb[(jl * 8 + mt * 2 + ih) * 2];
      mxs[mt] = s2.x; invs[mt] = s2.y;
    }
    f32x4 oacc[4];
#pragma unroll
    for (int mt = 0; mt < 4; ++mt) { f32x4 z = {0.f, 0.f, 0.f, 0.f}; oacc[mt] = z; }

    half8 vA0, vA1, rA0, rA1; float lA[8];
    half8 vB0, vB1, rB0, rB1; float lB[8];
    auto loadit = [&](int f, half8& v0, half8& v1, half8& r0, half8& r1, float* la) {
      const float* Lf = Lp + f * 512;
      const f16* Rf = Rp + f * 512;
      const f16* vf = vb + (int64_t)f * 64 * 64;
      v0 = *(const half8*)&vf[quad * 8];
      v1 = *(const half8*)&vf[32 + quad * 8];
      r0 = *(const half8*)&Rf[quad * 64 + jl * 8];
      r1 = *(const half8*)&Rf[(4 + quad) * 64 + jl * 8];
#pragma unroll
      for (int mt = 0; mt < 4; ++mt) {
        la[mt]     = Lf[jl * 64 + quad * 8 + mt * 2 + ih];
        la[4 + mt] = Lf[jl * 64 + (4 + quad) * 8 + mt * 2 + ih];
      }
    };
    auto compit = [&](half8& v0, half8& v1, half8& r0, half8& r1, float* la) {
#pragma unroll
      for (int mt = 0; mt < 4; ++mt) {
        f16 Lh0 = (f16)(__expf(la[mt] - mxs[mt]) * invs[mt]);
        f16 Lh1 = (f16)(__expf(la[4 + mt] - mxs[mt]) * invs[mt]);
        half8 w0, w1;
#pragma unroll
        for (int l = 0; l < 8; ++l) { w0[l] = r0[l] * Lh0; w1[l] = r1[l] * Lh1; }
        oacc[mt] = mfma16(w0, v0, oacc[mt]);
        oacc[mt] = mfma16(w1, v1, oacc[mt]);
      }
    };
    int f = fg;
    if (f <= g) {
      loadit(f, vA0, vA1, rA0, rA1, lA);
      while (true) {
        if (f + 2 <= g) {
          loadit(f + 2, vB0, vB1, rB0, rB1, lB);
          compit(vA0, vA1, rA0, rA1, lA);
          f += 2;
        } else { compit(vA0, vA1, rA0, rA1, lA); break; }
        if (f + 2 <= g) {
          loadit(f + 2, vA0, vA1, rA0, rA1, lA);
          compit(vB0, vB1, rB0, rB1, lB);
          f += 2;
        } else { compit(vB0, vB1, rB0, rB1, lB); break; }
      }
    }
    // fence: ensure previous phase's red consumers finished, then merge
    __syncthreads();
    if (fg == 1) {
#pragma unroll
      for (int mt = 0; mt < 4; ++mt)
#pragma unroll
        for (int r2 = 0; r2 < 4; ++r2)
          red[(dw * 16 + mt * 4 + r2) * 64 + lane] = oacc[mt][r2];
    }
    __syncthreads();
    if (fg == 0) {
#pragma unroll
      for (int mt = 0; mt < 4; ++mt)
#pragma unroll
        for (int r2 = 0; r2 < 4; ++r2)
          oacc[mt][r2] += red[(dw * 16 + mt * 4 + r2) * 64 + lane];
      float* ob = out + (int64_t)((bh >> 4) * 2048 + g * 64) * 1024 + (bh & 15) * 64;
#pragma unroll
      for (int mt = 0; mt < 4; ++mt)
#pragma unroll
        for (int r2 = 0; r2 < 4; ++r2)
          ob[(int64_t)(mt * 16 + quad * 4 + r2) * 1024 + dw * 16 + ln] = oacc[mt][r2];
    }
  }
}

// ---------------------------------------------------------------------------
extern "C" void kernel_launch(void* const* d_in, const int* in_sizes, int n_in,
                              void* d_out, int out_size, void* d_ws, size_t ws_size,
                              hipStream_t stream) {
  const float* x    = (const float*)d_in[0];
  const float* cosg = (const float*)d_in[1];
  const float* sing = (const float*)d_in[2];
  const float* wq   = (const float*)d_in[3];
  const float* wk   = (const float*)d_in[4];
  const float* wv   = (const float*)d_in[5];
  const float* gq   = (const float*)d_in[6];
  const float* gk   = (const float*)d_in[7];
  float* out = (float*)d_out;

  char* ws = (char*)d_ws;
  f16*   xh     = (f16*)(ws);                     // 8,388,608 B
  f16*   wcat   = (f16*)(ws + 8388608);           // 6,291,456 B
  float* P      = (float*)(ws + 14680064);        // 50,331,648 B (dead after K3)
  f16*   Rg     = (f16*)(ws + 14680064);          // 17,301,504 B (aliases P)
  float* stats1 = (float*)(ws + 31981568);        // 524,288 B
  float* stats2 = (float*)(ws + 32505856);        // 524,288 B
  f16*   qh     = (f16*)(ws + 65011712);          // 8,388,608 B
  f16*   kh     = (f16*)(ws + 73400320);          // 8,388,608 B
  f16*   vth    = (f16*)(ws + 81788928);          // 8,388,608 B
  float* Lg     = (float*)(ws + 90177536);        // 34,603,008 B -> end ~119 MB

  hipLaunchKernelGGL(k_cast, dim3(1024), dim3(256), 0, stream, x, wq, wk, wv, xh, wcat);
  hipLaunchKernelGGL(k_gemm, dim3(768), dim3(256), 0, stream, xh, wcat, P);
  hipLaunchKernelGGL(k_epilogue, dim3(1024), dim3(256), 0, stream,
                     P, cosg, sing, gq, gk, qh, kh, vth);
  hipLaunchKernelGGL(k_phase, dim3(16896), dim3(64), 0, stream, qh, kh, Lg, Rg, stats1, 0);
  hipLaunchKernelGGL(k_stats, dim3(1024), dim3(256), 0, stream, Lg, stats1);
  hipLaunchKernelGGL(k_phase, dim3(16896), dim3(64), 0, stream, qh, kh, Lg, Rg, stats1, 1);
  hipLaunchKernelGGL(k_stats, dim3(1024), dim3(256), 0, stream, Lg, stats2);
  hipLaunchKernelGGL(k_out, dim3(512), dim3(512), 0, stream, Lg, Rg, vth, stats2, out);
}

// Round 7
// 291.619 us; speedup vs baseline: 2.8018x; 1.0628x over previous
//
#include <hip/hip_runtime.h>
#include <stdint.h>

typedef _Float16 f16;
typedef _Float16 half8 __attribute__((ext_vector_type(8)));
typedef _Float16 half4v __attribute__((ext_vector_type(4)));
typedef float f32x4 __attribute__((ext_vector_type(4)));

#define DEV static __device__ __forceinline__

DEV f32x4 mfma16(half8 a, half8 b, f32x4 c) {
  return __builtin_amdgcn_mfma_f32_16x16x32_f16(a, b, c, 0, 0, 0);
}

// async global->LDS 16B: LDS dst is wave-uniform base + lane*16
DEV void cp16(const f16* g, f16* l) {
  __builtin_amdgcn_global_load_lds(
      (const __attribute__((address_space(1))) void*)g,
      (__attribute__((address_space(3))) void*)l, 16, 0, 0);
}

// Problem constants: B=2, S=2048, DIM=1024, H=16, D=64, B1=B2=8, F=32, ITERS=2
// seq position s = g*64 + i*8 + j ; kv position = f*64 + k*8 + l
// Packed slices: slice(bh,g,f) base = (bh*528 + g(g+1)/2 + f) * 512 elems.
// L slice layout: o = j*64 + k*8 + i (fp32 logits)
// R slice layout: o = k*64 + j*8 + l (f16 probs)
// Pg slice layout: o = j*64 + k*8 + ii, f16, where stored ii=ih*4+mt holds
//   true i = mt*2+ih  (so k_out lane (jl,ih) loads 8B of exactly its 4 vals)
// vth layout: [bh][f][d][64] f16.

// ---------------- K1: cast x, wq|wk|wv -> fp16 ----------------
__global__ __launch_bounds__(256) void k_cast(
    const float* __restrict__ x, const float* __restrict__ wq,
    const float* __restrict__ wk, const float* __restrict__ wv,
    f16* __restrict__ xh, f16* __restrict__ wcat) {
  const int64_t nx4 = 4194304 / 4;
  const int64_t nw4 = 1048576 / 4;
  int64_t stride = (int64_t)gridDim.x * blockDim.x;
  for (int64_t i = (int64_t)blockIdx.x * blockDim.x + threadIdx.x;
       i < nx4 + 3 * nw4; i += stride) {
    const float* src; f16* dst; int64_t off;
    if (i < nx4) { src = x; dst = xh; off = i; }
    else {
      int64_t r = i - nx4;
      int ws_ = (int)(r / nw4);
      off = r - (int64_t)ws_ * nw4;
      src = (ws_ == 0) ? wq : ((ws_ == 1) ? wk : wv);
      dst = wcat + (int64_t)ws_ * 1048576;
    }
    float4 v = ((const float4*)src)[off];
    half4v hh; hh[0] = (f16)v.x; hh[1] = (f16)v.y; hh[2] = (f16)v.z; hh[3] = (f16)v.w;
    ((half4v*)dst)[off] = hh;
  }
}

// ---------------- K2: P = xh @ wcat^T, async-staged, XOR-swizzled LDS -------
// LDS layout (per tile row): chunk c of row stored at position c ^ (row&7);
// staging lane (t) covers row it*32 + (t>>3), stored chunk t&7, so it must
// fetch source chunk (t&7) ^ ((t>>3)&7). Fragment reads land 2-way (free).
__global__ __launch_bounds__(256) void k_gemm(
    const f16* __restrict__ A, const f16* __restrict__ Bm,
    float* __restrict__ P) {
  __shared__ f16 As[128 * 64];   // 16 KB, unpadded, swizzled
  __shared__ f16 Bs[128 * 64];
  const int t = threadIdx.x;
  const int wave = t >> 6, lane = t & 63, quad = lane >> 4, ln = lane & 15;
  const int tM = blockIdx.x / 24, tN = blockIdx.x % 24;
  const int wm = wave >> 1, wn = wave & 1;
  f32x4 acc[4][4];
#pragma unroll
  for (int a = 0; a < 4; ++a)
#pragma unroll
    for (int b = 0; b < 4; ++b) { f32x4 z = {0.f, 0.f, 0.f, 0.f}; acc[a][b] = z; }
  const int srow = t >> 3;                 // 0..31
  const int c = (t & 7) ^ (srow & 7);      // source chunk for this lane
  const f16* Ag = A + (int64_t)(tM * 128 + srow) * 1024 + c * 8;
  const f16* Bg = Bm + (int64_t)(tN * 128 + srow) * 1024 + c * 8;
  for (int kt = 0; kt < 16; ++kt) {
    __syncthreads();   // previous MFMA reads done before LDS overwrite
#pragma unroll
    for (int it = 0; it < 4; ++it) {
      cp16(Ag + (int64_t)it * 32 * 1024 + kt * 64, &As[it * 2048 + wave * 512]);
      cp16(Bg + (int64_t)it * 32 * 1024 + kt * 64, &Bs[it * 2048 + wave * 512]);
    }
    __syncthreads();   // drains vmcnt(0): staged data visible
#pragma unroll
    for (int ks = 0; ks < 2; ++ks) {
      const int cs = ((ks * 4 + quad) ^ (ln & 7)) * 8;
      half8 bf[4];
#pragma unroll
      for (int tn = 0; tn < 4; ++tn)
        bf[tn] = *(const half8*)&Bs[(wn * 64 + tn * 16 + ln) * 64 + cs];
#pragma unroll
      for (int tm = 0; tm < 4; ++tm) {
        half8 af = *(const half8*)&As[(wm * 64 + tm * 16 + ln) * 64 + cs];
#pragma unroll
        for (int tn = 0; tn < 4; ++tn)
          acc[tm][tn] = mfma16(af, bf[tn], acc[tm][tn]);
      }
    }
  }
#pragma unroll
  for (int tm = 0; tm < 4; ++tm)
#pragma unroll
    for (int tn = 0; tn < 4; ++tn)
#pragma unroll
      for (int r2 = 0; r2 < 4; ++r2) {
        int row = tM * 128 + wm * 64 + tm * 16 + quad * 4 + r2;
        int col = tN * 128 + wn * 64 + tn * 16 + ln;
        P[(int64_t)row * 3072 + col] = acc[tm][tn][r2];
      }
}

// ---------------- K3: rmsnorm+rope+scale for q,k; v -> [bh][f][d][64] f16 ---
__global__ __launch_bounds__(256) void k_epilogue(
    const float* __restrict__ P, const float* __restrict__ cosg,
    const float* __restrict__ sing, const float* __restrict__ gq,
    const float* __restrict__ gk, f16* __restrict__ qh,
    f16* __restrict__ kh, f16* __restrict__ vth) {
  __shared__ f16 vbuf[64 * 72];
  const int t = threadIdx.x;
  const int bid = blockIdx.x;
  const int st = bid & 31, h = (bid >> 5) & 15, b = bid >> 9;
  const int r = t >> 2, qt = t & 3, c0 = qt * 16;
  const int s = st * 64 + r;
  const int64_t rowbase = (int64_t)(b * 2048 + s) * 3072;
  const float scale = 0.35355339059327373f;  // 64^-0.25
#pragma unroll
  for (int m = 0; m < 2; ++m) {
    const float* gv = (m == 0) ? gq : gk;
    const int colbase = m * 1024 + h * 64 + c0;
    float xv[16];
#pragma unroll
    for (int c = 0; c < 4; ++c) {
      float4 v4 = *(const float4*)&P[rowbase + colbase + c * 4];
      xv[c * 4 + 0] = v4.x; xv[c * 4 + 1] = v4.y;
      xv[c * 4 + 2] = v4.z; xv[c * 4 + 3] = v4.w;
    }
    float ss = 0.f;
#pragma unroll
    for (int c = 0; c < 16; ++c) ss += xv[c] * xv[c];
    ss += __shfl_xor(ss, 1, 64);
    ss += __shfl_xor(ss, 2, 64);
    float rs = rsqrtf(ss * (1.f / 64.f) + 1e-6f);
    alignas(16) f16 res[16];
#pragma unroll
    for (int ci = 0; ci < 16; ci += 2) {
      int d0 = c0 + ci, d1 = d0 + 1;
      float av = xv[ci] * rs * gv[d0];
      float bv = xv[ci + 1] * rs * gv[d1];
      float c0v = cosg[s * 64 + d0], c1v = cosg[s * 64 + d1];
      float s0v = sing[s * 64 + d0], s1v = sing[s * 64 + d1];
      res[ci]     = (f16)((av * c0v - bv * s0v) * scale);
      res[ci + 1] = (f16)((bv * c1v + av * s1v) * scale);
    }
    f16* dst = ((m == 0) ? qh : kh) + (int64_t)((b * 16 + h) * 2048 + s) * 64 + c0;
    *(half8*)dst = *(const half8*)&res[0];
    *(half8*)(dst + 8) = *(const half8*)&res[8];
  }
  {
    const int colbase = 2048 + h * 64 + c0;
#pragma unroll
    for (int c = 0; c < 4; ++c) {
      float4 v4 = *(const float4*)&P[rowbase + colbase + c * 4];
      vbuf[(c0 + c * 4 + 0) * 72 + r] = (f16)v4.x;
      vbuf[(c0 + c * 4 + 1) * 72 + r] = (f16)v4.y;
      vbuf[(c0 + c * 4 + 2) * 72 + r] = (f16)v4.z;
      vbuf[(c0 + c * 4 + 3) * 72 + r] = (f16)v4.w;
    }
    __syncthreads();
    const int d = t >> 2, sc = qt * 16;
    alignas(16) f16 tmp[16];
#pragma unroll
    for (int ci = 0; ci < 16; ++ci) tmp[ci] = vbuf[d * 72 + sc + ci];
    f16* dst = vth + (int64_t)(((b * 16 + h) * 32 + st) * 64 + d) * 64 + sc;
    *(half8*)dst = *(const half8*)&tmp[0];
    *(half8*)(dst + 8) = *(const half8*)&tmp[8];
  }
}

// ---------------- K4: phase kernel — ONE WAVE per (bh,g,f) ------------------
__global__ __launch_bounds__(64) void k_phase(
    const f16* __restrict__ qh, const f16* __restrict__ kh,
    float* __restrict__ Lg, f16* __restrict__ Rg,
    const f16* __restrict__ Pg, int iter) {
  __shared__ float Sw[4416];   // 17664 B
  const int lane = threadIdx.x;
  const int quad = lane >> 4, ln = lane & 15;
  const int jr = lane >> 3, kr = lane & 7;   // lane = jr*8 + kr

  const int bh = blockIdx.x / 528;
  const int rem = blockIdx.x - bh * 528;
  int g = (int)((sqrtf(8.f * (float)rem + 1.f) - 1.f) * 0.5f);
  while ((g + 1) * (g + 2) / 2 <= rem) ++g;
  while (g * (g + 1) / 2 > rem) --g;
  const int f = rem - g * (g + 1) / 2;

  const f16* qg = qh + (int64_t)(bh * 2048 + g * 64) * 64;
  const f16* kf = kh + (int64_t)(bh * 2048 + f * 64) * 64;
  const int64_t sbase = ((int64_t)bh * 528 + ((g * (g + 1)) >> 1) + f) * 512;
  float* Lp = Lg + sbase;

  half8 afr[2][4], bfr[2][4];
#pragma unroll
  for (int ks = 0; ks < 2; ++ks)
#pragma unroll
    for (int t4 = 0; t4 < 4; ++t4) {
      afr[ks][t4] = *(const half8*)&qg[(t4 * 16 + ln) * 64 + ks * 32 + quad * 8];
      bfr[ks][t4] = *(const half8*)&kf[(t4 * 16 + ln) * 64 + ks * 32 + quad * 8];
    }
  float p[8], cR = 0.f;
  if (iter) {  // this lane's L-probs (precomputed f16, permuted layout)
    half8 ph = *(const half8*)&Pg[sbase + lane * 8];
    p[0] = (float)ph[0]; p[2] = (float)ph[1]; p[4] = (float)ph[2]; p[6] = (float)ph[3];
    p[1] = (float)ph[4]; p[3] = (float)ph[5]; p[5] = (float)ph[6]; p[7] = (float)ph[7];
#pragma unroll
    for (int i = 0; i < 8; ++i) cR += p[i];
  }
  f32x4 acc[4][4];
#pragma unroll
  for (int a = 0; a < 4; ++a)
#pragma unroll
    for (int b = 0; b < 4; ++b) { f32x4 z = {0.f, 0.f, 0.f, 0.f}; acc[a][b] = z; }
#pragma unroll
  for (int ks = 0; ks < 2; ++ks)
#pragma unroll
    for (int mt = 0; mt < 4; ++mt)
#pragma unroll
      for (int nt = 0; nt < 4; ++nt)
        acc[mt][nt] = mfma16(afr[ks][mt], bfr[ks][nt], acc[mt][nt]);
  const int wbase = (quad >> 1) * 552 + (quad & 1) * 272 + (ln >> 3) * 8 + (ln & 7);
#pragma unroll
  for (int mt = 0; mt < 4; ++mt)
#pragma unroll
    for (int nt = 0; nt < 4; ++nt)
#pragma unroll
      for (int r2 = 0; r2 < 4; ++r2)
        Sw[wbase + mt * 1104 + nt * 16 + r2 * 68] = acc[mt][nt][r2];
  __syncthreads();
  float Sr[8][8];
  const int rb = jr * 68 + kr * 8;
#pragma unroll
  for (int i = 0; i < 8; ++i) {
    *(float4*)&Sr[i][0] = *(const float4*)&Sw[i * 552 + rb];
    *(float4*)&Sr[i][4] = *(const float4*)&Sw[i * 552 + rb + 4];
  }
  float va[8];
  if (!iter) {
    float4 d0 = *(const float4*)&Sw[kr * 552 + rb];
    float4 d1 = *(const float4*)&Sw[kr * 552 + rb + 4];
    va[0] = d0.x; va[1] = d0.y; va[2] = d0.z; va[3] = d0.w;
    va[4] = d1.x; va[5] = d1.y; va[6] = d1.z; va[7] = d1.w;
    const float sc = 1.f / (1.f + 1e-6f);
#pragma unroll
    for (int l = 0; l < 8; ++l) va[l] *= sc;
  } else {
    float bR[8];
#pragma unroll
    for (int l = 0; l < 8; ++l) bR[l] = 0.f;
#pragma unroll
    for (int i = 0; i < 8; ++i)
#pragma unroll
      for (int l = 0; l < 8; ++l) bR[l] += p[i] * Sr[i][l];
    const float rc = 1.f / (cR + 1e-6f);
#pragma unroll
    for (int l = 0; l < 8; ++l) va[l] = bR[l] * rc;
  }
  float mx = va[0];
#pragma unroll
  for (int l = 1; l < 8; ++l) mx = fmaxf(mx, va[l]);
  float ex[8], sm = 0.f;
#pragma unroll
  for (int l = 0; l < 8; ++l) { ex[l] = __expf(va[l] - mx); sm += ex[l]; }
  const float inv = 1.f / sm;
  float rr[8], rl = 0.f;
#pragma unroll
  for (int l = 0; l < 8; ++l) {
    rr[l] = ex[l] * inv;
    rl += rr[l] * __logf(fmaxf(rr[l], 1e-30f));
  }
  if (iter) {
    half8 r8;
#pragma unroll
    for (int l = 0; l < 8; ++l) r8[l] = (f16)rr[l];
    *(half8*)&Rg[sbase + kr * 64 + jr * 8] = r8;
  }
  float bl[8];
#pragma unroll
  for (int i = 0; i < 8; ++i) {
    float s = 0.f;
#pragma unroll
    for (int l = 0; l < 8; ++l) s += rr[l] * Sr[i][l];
    bl[i] = s - rl;
  }
  *(float4*)&Lp[lane * 8]     = *(const float4*)&bl[0];
  *(float4*)&Lp[lane * 8 + 4] = *(const float4*)&bl[4];
}

// ---------------- K5: joint softmax -> f16 probs Pg (permuted layout) -------
__global__ __launch_bounds__(256) void k_probs(
    const float* __restrict__ Lg, f16* __restrict__ Pg) {
  __shared__ float Ls[32 * 546];
  __shared__ float stt[128];           // [j*8+i]{mx, 1/sum}
  const int t = threadIdx.x;
  const int g = 31 - (blockIdx.x & 31), bh = blockIdx.x >> 5;
  const int64_t sb = ((int64_t)bh * 528 + ((g * (g + 1)) >> 1)) * 512;
  const float* Lp = Lg + sb;
  for (int f = 0; f <= g; ++f) {
    const int o = 2 * t;
    *(float2*)&Ls[f * 546 + (o >> 6) * 68 + (o & 63)] = *(const float2*)&Lp[f * 512 + o];
  }
  __syncthreads();
  {
    const int p = t >> 2, sub = t & 3;
    const int base = (p >> 3) * 68 + (p & 7);
    float mx = -1e30f;
    for (int f = sub; f <= g; f += 4)
#pragma unroll
      for (int k_ = 0; k_ < 8; ++k_)
        mx = fmaxf(mx, Ls[f * 546 + base + k_ * 8]);
    mx = fmaxf(mx, __shfl_xor(mx, 1, 64));
    mx = fmaxf(mx, __shfl_xor(mx, 2, 64));
    float se = 0.f;
    for (int f = sub; f <= g; f += 4)
#pragma unroll
      for (int k_ = 0; k_ < 8; ++k_)
        se += __expf(Ls[f * 546 + base + k_ * 8] - mx);
    se += __shfl_xor(se, 1, 64);
    se += __shfl_xor(se, 2, 64);
    if (sub == 0) { stt[p * 2] = mx; stt[p * 2 + 1] = 1.f / se; }
  }
  __syncthreads();
  {
    const int r = t & 63, fq = t >> 6;
    const int j = r >> 3, k_ = r & 7;
    float mx[8], inv[8];
#pragma unroll
    for (int i = 0; i < 8; ++i) {
      mx[i] = stt[(j * 8 + i) * 2];
      inv[i] = stt[(j * 8 + i) * 2 + 1];
    }
    for (int fb = fq; fb <= g; fb += 4) {
      const float* row = &Ls[fb * 546 + j * 68 + k_ * 8];
      float pr[8];
#pragma unroll
      for (int i = 0; i < 8; ++i) pr[i] = __expf(row[i] - mx[i]) * inv[i];
      half8 st8;
      st8[0] = (f16)pr[0]; st8[1] = (f16)pr[2]; st8[2] = (f16)pr[4]; st8[3] = (f16)pr[6];
      st8[4] = (f16)pr[1]; st8[5] = (f16)pr[3]; st8[6] = (f16)pr[5]; st8[7] = (f16)pr[7];
      *(half8*)&Pg[sb + (int64_t)fb * 512 + r * 8] = st8;
    }
  }
}

// ---------------- K6: output — g-paired, f16 probs, 6 loads/iter, no exp ----
__global__ __launch_bounds__(512) void k_out(
    const f16* __restrict__ Pg, const f16* __restrict__ Rg,
    const f16* __restrict__ vth, float* __restrict__ out) {
  __shared__ float red[64 * 64];   // 16 KB
  const int t = threadIdx.x;
  const int wave = t >> 6, lane = t & 63, quad = lane >> 4, ln = lane & 15;
  const int fg = wave >> 2, dw = wave & 3;
  const int bh = blockIdx.x >> 4, G = blockIdx.x & 15;
  const int jl = ln & 7, ih = ln >> 3;
  const f16* vb = vth + ((int64_t)bh * 32 * 64 + dw * 16 + ln) * 64;

#pragma unroll 1
  for (int ph = 0; ph < 2; ++ph) {
    const int g = ph ? G : 31 - G;
    const int64_t sbase = ((int64_t)bh * 528 + ((g * (g + 1)) >> 1)) * 512;
    const f16* Pp = Pg + sbase;
    const f16* Rp = Rg + sbase;
    f32x4 oacc[4];
#pragma unroll
    for (int mt = 0; mt < 4; ++mt) { f32x4 z = {0.f, 0.f, 0.f, 0.f}; oacc[mt] = z; }

    half8 vA0, vA1, rA0, rA1; half4v pA0, pA1;
    half8 vB0, vB1, rB0, rB1; half4v pB0, pB1;
    auto loadit = [&](int f, half8& v0, half8& v1, half8& r0, half8& r1,
                      half4v& p0, half4v& p1) {
      const f16* Pf = Pp + f * 512;
      const f16* Rf = Rp + f * 512;
      const f16* vf = vb + (int64_t)f * 64 * 64;
      v0 = *(const half8*)&vf[quad * 8];
      v1 = *(const half8*)&vf[32 + quad * 8];
      r0 = *(const half8*)&Rf[quad * 64 + jl * 8];
      r1 = *(const half8*)&Rf[(4 + quad) * 64 + jl * 8];
      p0 = *(const half4v*)&Pf[jl * 64 + quad * 8 + ih * 4];
      p1 = *(const half4v*)&Pf[jl * 64 + (4 + quad) * 8 + ih * 4];
    };
    auto compit = [&](half8& v0, half8& v1, half8& r0, half8& r1,
                      half4v& p0, half4v& p1) {
#pragma unroll
      for (int mt = 0; mt < 4; ++mt) {
        const f16 Lh0 = p0[mt], Lh1 = p1[mt];
        half8 w0, w1;
#pragma unroll
        for (int l = 0; l < 8; ++l) { w0[l] = r0[l] * Lh0; w1[l] = r1[l] * Lh1; }
        oacc[mt] = mfma16(w0, v0, oacc[mt]);
        oacc[mt] = mfma16(w1, v1, oacc[mt]);
      }
    };
    int f = fg;
    if (f <= g) {
      loadit(f, vA0, vA1, rA0, rA1, pA0, pA1);
      while (true) {
        if (f + 2 <= g) {
          loadit(f + 2, vB0, vB1, rB0, rB1, pB0, pB1);
          compit(vA0, vA1, rA0, rA1, pA0, pA1);
          f += 2;
        } else { compit(vA0, vA1, rA0, rA1, pA0, pA1); break; }
        if (f + 2 <= g) {
          loadit(f + 2, vA0, vA1, rA0, rA1, pA0, pA1);
          compit(vB0, vB1, rB0, rB1, pB0, pB1);
          f += 2;
        } else { compit(vB0, vB1, rB0, rB1, pB0, pB1); break; }
      }
    }
    __syncthreads();
    if (fg == 1) {
#pragma unroll
      for (int mt = 0; mt < 4; ++mt)
#pragma unroll
        for (int r2 = 0; r2 < 4; ++r2)
          red[(dw * 16 + mt * 4 + r2) * 64 + lane] = oacc[mt][r2];
    }
    __syncthreads();
    if (fg == 0) {
#pragma unroll
      for (int mt = 0; mt < 4; ++mt)
#pragma unroll
        for (int r2 = 0; r2 < 4; ++r2)
          oacc[mt][r2] += red[(dw * 16 + mt * 4 + r2) * 64 + lane];
      float* ob = out + (int64_t)((bh >> 4) * 2048 + g * 64) * 1024 + (bh & 15) * 64;
#pragma unroll
      for (int mt = 0; mt < 4; ++mt)
#pragma unroll
        for (int r2 = 0; r2 < 4; ++r2)
          ob[(int64_t)(mt * 16 + quad * 4 + r2) * 1024 + dw * 16 + ln] = oacc[mt][r2];
    }
  }
}

// ---------------------------------------------------------------------------
extern "C" void kernel_launch(void* const* d_in, const int* in_sizes, int n_in,
                              void* d_out, int out_size, void* d_ws, size_t ws_size,
                              hipStream_t stream) {
  const float* x    = (const float*)d_in[0];
  const float* cosg = (const float*)d_in[1];
  const float* sing = (const float*)d_in[2];
  const float* wq   = (const float*)d_in[3];
  const float* wk   = (const float*)d_in[4];
  const float* wv   = (const float*)d_in[5];
  const float* gq   = (const float*)d_in[6];
  const float* gk   = (const float*)d_in[7];
  float* out = (float*)d_out;

  char* ws = (char*)d_ws;
  f16*   xh   = (f16*)(ws);                     // 8,388,608 B
  f16*   wcat = (f16*)(ws + 8388608);           // 6,291,456 B
  float* P    = (float*)(ws + 14680064);        // 50,331,648 B (dead after K3)
  f16*   Rg   = (f16*)(ws + 14680064);          // 17,301,504 B (aliases P)
  f16*   Pg   = (f16*)(ws + 31981568);          // 17,301,504 B (aliases P)
  f16*   qh   = (f16*)(ws + 65011712);          // 8,388,608 B
  f16*   kh   = (f16*)(ws + 73400320);          // 8,388,608 B
  f16*   vth  = (f16*)(ws + 81788928);          // 8,388,608 B
  float* Lg   = (float*)(ws + 90177536);        // 34,603,008 B -> end ~119 MB

  hipLaunchKernelGGL(k_cast, dim3(1024), dim3(256), 0, stream, x, wq, wk, wv, xh, wcat);
  hipLaunchKernelGGL(k_gemm, dim3(768), dim3(256), 0, stream, xh, wcat, P);
  hipLaunchKernelGGL(k_epilogue, dim3(1024), dim3(256), 0, stream,
                     P, cosg, sing, gq, gk, qh, kh, vth);
  hipLaunchKernelGGL(k_phase, dim3(16896), dim3(64), 0, stream, qh, kh, Lg, Rg, Pg, 0);
  hipLaunchKernelGGL(k_probs, dim3(1024), dim3(256), 0, stream, Lg, Pg);
  hipLaunchKernelGGL(k_phase, dim3(16896), dim3(64), 0, stream, qh, kh, Lg, Rg, Pg, 1);
  hipLaunchKernelGGL(k_probs, dim3(1024), dim3(256), 0, stream, Lg, Pg);
  hipLaunchKernelGGL(k_out, dim3(512), dim3(512), 0, stream, Pg, Rg, vth, out);
}

// Round 8
// 265.279 us; speedup vs baseline: 3.0800x; 1.0993x over previous
//
#include <hip/hip_runtime.h>
#include <stdint.h>

typedef _Float16 f16;
typedef _Float16 half8 __attribute__((ext_vector_type(8)));
typedef _Float16 half4v __attribute__((ext_vector_type(4)));
typedef float f32x4 __attribute__((ext_vector_type(4)));

#define DEV static __device__ __forceinline__

DEV f32x4 mfma16(half8 a, half8 b, f32x4 c) {
  return __builtin_amdgcn_mfma_f32_16x16x32_f16(a, b, c, 0, 0, 0);
}

// async global->LDS 16B: LDS dst is wave-uniform base + lane*16
DEV void cp16(const f16* g, f16* l) {
  __builtin_amdgcn_global_load_lds(
      (const __attribute__((address_space(1))) void*)g,
      (__attribute__((address_space(3))) void*)l, 16, 0, 0);
}

// Problem constants: B=2, S=2048, DIM=1024, H=16, D=64, B1=B2=8, F=32, ITERS=2
// seq position s = g*64 + i*8 + j ; kv position = f*64 + k*8 + l
// Packed slices: slice(bh,g,f) base = (bh*528 + g(g+1)/2 + f) * 512 elems.
// L slice layout: o = j*64 + k*8 + i (f16 logits)
// R slice layout: o = k*64 + j*8 + l (f16 probs)
// Pg slice layout: o = j*64 + k*8 + ii, f16, stored ii=ih*4+mt holds true
//   i = mt*2+ih  (k_out lane (jl,ih) loads 8B of exactly its 4 values)
// vth layout: [bh][f][d][64] f16.

// ---------------- K1: cast x, wq|wk|wv -> fp16 ----------------
__global__ __launch_bounds__(256) void k_cast(
    const float* __restrict__ x, const float* __restrict__ wq,
    const float* __restrict__ wk, const float* __restrict__ wv,
    f16* __restrict__ xh, f16* __restrict__ wcat) {
  const int64_t nx4 = 4194304 / 4;
  const int64_t nw4 = 1048576 / 4;
  int64_t stride = (int64_t)gridDim.x * blockDim.x;
  for (int64_t i = (int64_t)blockIdx.x * blockDim.x + threadIdx.x;
       i < nx4 + 3 * nw4; i += stride) {
    const float* src; f16* dst; int64_t off;
    if (i < nx4) { src = x; dst = xh; off = i; }
    else {
      int64_t r = i - nx4;
      int ws_ = (int)(r / nw4);
      off = r - (int64_t)ws_ * nw4;
      src = (ws_ == 0) ? wq : ((ws_ == 1) ? wk : wv);
      dst = wcat + (int64_t)ws_ * 1048576;
    }
    float4 v = ((const float4*)src)[off];
    half4v hh; hh[0] = (f16)v.x; hh[1] = (f16)v.y; hh[2] = (f16)v.z; hh[3] = (f16)v.w;
    ((half4v*)dst)[off] = hh;
  }
}

// ---------------- K2: P = xh @ wcat^T, async-staged, XOR-swizzled LDS -------
__global__ __launch_bounds__(256) void k_gemm(
    const f16* __restrict__ A, const f16* __restrict__ Bm,
    float* __restrict__ P) {
  __shared__ f16 As[128 * 64];   // 16 KB, unpadded, swizzled
  __shared__ f16 Bs[128 * 64];
  const int t = threadIdx.x;
  const int wave = t >> 6, lane = t & 63, quad = lane >> 4, ln = lane & 15;
  const int tM = blockIdx.x / 24, tN = blockIdx.x % 24;
  const int wm = wave >> 1, wn = wave & 1;
  f32x4 acc[4][4];
#pragma unroll
  for (int a = 0; a < 4; ++a)
#pragma unroll
    for (int b = 0; b < 4; ++b) { f32x4 z = {0.f, 0.f, 0.f, 0.f}; acc[a][b] = z; }
  const int srow = t >> 3;
  const int c = (t & 7) ^ (srow & 7);
  const f16* Ag = A + (int64_t)(tM * 128 + srow) * 1024 + c * 8;
  const f16* Bg = Bm + (int64_t)(tN * 128 + srow) * 1024 + c * 8;
  for (int kt = 0; kt < 16; ++kt) {
    __syncthreads();
#pragma unroll
    for (int it = 0; it < 4; ++it) {
      cp16(Ag + (int64_t)it * 32 * 1024 + kt * 64, &As[it * 2048 + wave * 512]);
      cp16(Bg + (int64_t)it * 32 * 1024 + kt * 64, &Bs[it * 2048 + wave * 512]);
    }
    __syncthreads();
#pragma unroll
    for (int ks = 0; ks < 2; ++ks) {
      const int cs = ((ks * 4 + quad) ^ (ln & 7)) * 8;
      half8 bf[4];
#pragma unroll
      for (int tn = 0; tn < 4; ++tn)
        bf[tn] = *(const half8*)&Bs[(wn * 64 + tn * 16 + ln) * 64 + cs];
#pragma unroll
      for (int tm = 0; tm < 4; ++tm) {
        half8 af = *(const half8*)&As[(wm * 64 + tm * 16 + ln) * 64 + cs];
#pragma unroll
        for (int tn = 0; tn < 4; ++tn)
          acc[tm][tn] = mfma16(af, bf[tn], acc[tm][tn]);
      }
    }
  }
#pragma unroll
  for (int tm = 0; tm < 4; ++tm)
#pragma unroll
    for (int tn = 0; tn < 4; ++tn)
#pragma unroll
      for (int r2 = 0; r2 < 4; ++r2) {
        int row = tM * 128 + wm * 64 + tm * 16 + quad * 4 + r2;
        int col = tN * 128 + wn * 64 + tn * 16 + ln;
        P[(int64_t)row * 3072 + col] = acc[tm][tn][r2];
      }
}

// ---------------- K3: rmsnorm+rope+scale for q,k; v -> [bh][f][d][64] f16 ---
__global__ __launch_bounds__(256) void k_epilogue(
    const float* __restrict__ P, const float* __restrict__ cosg,
    const float* __restrict__ sing, const float* __restrict__ gq,
    const float* __restrict__ gk, f16* __restrict__ qh,
    f16* __restrict__ kh, f16* __restrict__ vth) {
  __shared__ f16 vbuf[64 * 72];
  const int t = threadIdx.x;
  const int bid = blockIdx.x;
  const int st = bid & 31, h = (bid >> 5) & 15, b = bid >> 9;
  const int r = t >> 2, qt = t & 3, c0 = qt * 16;
  const int s = st * 64 + r;
  const int64_t rowbase = (int64_t)(b * 2048 + s) * 3072;
  const float scale = 0.35355339059327373f;  // 64^-0.25
#pragma unroll
  for (int m = 0; m < 2; ++m) {
    const float* gv = (m == 0) ? gq : gk;
    const int colbase = m * 1024 + h * 64 + c0;
    float xv[16];
#pragma unroll
    for (int c = 0; c < 4; ++c) {
      float4 v4 = *(const float4*)&P[rowbase + colbase + c * 4];
      xv[c * 4 + 0] = v4.x; xv[c * 4 + 1] = v4.y;
      xv[c * 4 + 2] = v4.z; xv[c * 4 + 3] = v4.w;
    }
    float ss = 0.f;
#pragma unroll
    for (int c = 0; c < 16; ++c) ss += xv[c] * xv[c];
    ss += __shfl_xor(ss, 1, 64);
    ss += __shfl_xor(ss, 2, 64);
    float rs = rsqrtf(ss * (1.f / 64.f) + 1e-6f);
    alignas(16) f16 res[16];
#pragma unroll
    for (int ci = 0; ci < 16; ci += 2) {
      int d0 = c0 + ci, d1 = d0 + 1;
      float av = xv[ci] * rs * gv[d0];
      float bv = xv[ci + 1] * rs * gv[d1];
      float c0v = cosg[s * 64 + d0], c1v = cosg[s * 64 + d1];
      float s0v = sing[s * 64 + d0], s1v = sing[s * 64 + d1];
      res[ci]     = (f16)((av * c0v - bv * s0v) * scale);
      res[ci + 1] = (f16)((bv * c1v + av * s1v) * scale);
    }
    f16* dst = ((m == 0) ? qh : kh) + (int64_t)((b * 16 + h) * 2048 + s) * 64 + c0;
    *(half8*)dst = *(const half8*)&res[0];
    *(half8*)(dst + 8) = *(const half8*)&res[8];
  }
  {
    const int colbase = 2048 + h * 64 + c0;
#pragma unroll
    for (int c = 0; c < 4; ++c) {
      float4 v4 = *(const float4*)&P[rowbase + colbase + c * 4];
      vbuf[(c0 + c * 4 + 0) * 72 + r] = (f16)v4.x;
      vbuf[(c0 + c * 4 + 1) * 72 + r] = (f16)v4.y;
      vbuf[(c0 + c * 4 + 2) * 72 + r] = (f16)v4.z;
      vbuf[(c0 + c * 4 + 3) * 72 + r] = (f16)v4.w;
    }
    __syncthreads();
    const int d = t >> 2, sc = qt * 16;
    alignas(16) f16 tmp[16];
#pragma unroll
    for (int ci = 0; ci < 16; ++ci) tmp[ci] = vbuf[d * 72 + sc + ci];
    f16* dst = vth + (int64_t)(((b * 16 + h) * 32 + st) * 64 + d) * 64 + sc;
    *(half8*)dst = *(const half8*)&tmp[0];
    *(half8*)(dst + 8) = *(const half8*)&tmp[8];
  }
}

// ---------------- K4: phase kernel — ONE WAVE per (bh,g,f), f16 S in LDS ----
// Sw layout (f16 index): i*584 + j*72 + k*8 + l  (rows 16B-aligned; b128 row
// reads are uniform 8 words/bank = optimal). 9.3 KB -> ~16 blocks/CU.
__global__ __launch_bounds__(64) void k_phase(
    const f16* __restrict__ qh, const f16* __restrict__ kh,
    f16* __restrict__ Lg, f16* __restrict__ Rg,
    const f16* __restrict__ Pg, int iter) {
  __shared__ f16 Sw[8 * 584];   // 9344 B
  const int lane = threadIdx.x;
  const int quad = lane >> 4, ln = lane & 15;
  const int jr = lane >> 3, kr = lane & 7;   // lane = jr*8 + kr

  const int bh = blockIdx.x / 528;
  const int rem = blockIdx.x - bh * 528;
  int g = (int)((sqrtf(8.f * (float)rem + 1.f) - 1.f) * 0.5f);
  while ((g + 1) * (g + 2) / 2 <= rem) ++g;
  while (g * (g + 1) / 2 > rem) --g;
  const int f = rem - g * (g + 1) / 2;

  const f16* qg = qh + (int64_t)(bh * 2048 + g * 64) * 64;
  const f16* kf = kh + (int64_t)(bh * 2048 + f * 64) * 64;
  const int64_t sbase = ((int64_t)bh * 528 + ((g * (g + 1)) >> 1) + f) * 512;
  f16* Lp = Lg + sbase;

  half8 afr[2][4], bfr[2][4];
#pragma unroll
  for (int ks = 0; ks < 2; ++ks)
#pragma unroll
    for (int t4 = 0; t4 < 4; ++t4) {
      afr[ks][t4] = *(const half8*)&qg[(t4 * 16 + ln) * 64 + ks * 32 + quad * 8];
      bfr[ks][t4] = *(const half8*)&kf[(t4 * 16 + ln) * 64 + ks * 32 + quad * 8];
    }
  float p[8], cR = 0.f;
  if (iter) {  // this lane's L-probs (precomputed f16, permuted layout)
    half8 ph = *(const half8*)&Pg[sbase + lane * 8];
    p[0] = (float)ph[0]; p[2] = (float)ph[1]; p[4] = (float)ph[2]; p[6] = (float)ph[3];
    p[1] = (float)ph[4]; p[3] = (float)ph[5]; p[5] = (float)ph[6]; p[7] = (float)ph[7];
#pragma unroll
    for (int i = 0; i < 8; ++i) cR += p[i];
  }
  f32x4 acc[4][4];
#pragma unroll
  for (int a = 0; a < 4; ++a)
#pragma unroll
    for (int b = 0; b < 4; ++b) { f32x4 z = {0.f, 0.f, 0.f, 0.f}; acc[a][b] = z; }
#pragma unroll
  for (int ks = 0; ks < 2; ++ks)
#pragma unroll
    for (int mt = 0; mt < 4; ++mt)
#pragma unroll
      for (int nt = 0; nt < 4; ++nt)
        acc[mt][nt] = mfma16(afr[ks][mt], bfr[ks][nt], acc[mt][nt]);
  // scatter store C-layout -> f16 Sw: m=(i,j) rows, n=(k,l) cols
#pragma unroll
  for (int nt = 0; nt < 4; ++nt) {
    const int n = nt * 16 + ln;
    const int cp = (n >> 3) * 8 + (n & 7);
#pragma unroll
    for (int mt = 0; mt < 4; ++mt)
#pragma unroll
      for (int r2 = 0; r2 < 4; ++r2) {
        const int m = mt * 16 + quad * 4 + r2;
        Sw[(m >> 3) * 584 + (m & 7) * 72 + cp] = (f16)acc[mt][nt][r2];
      }
  }
  __syncthreads();   // single wave: waitcnt + cheap barrier
  const int rb = jr * 72 + kr * 8;
  float va[8];
  if (!iter) {
    // L = block identity: bR[l] = S[(kr,jr)][(kr,l)], cR = 1
    half8 s8 = *(const half8*)&Sw[kr * 584 + rb];
    const float sc = 1.f / (1.f + 1e-6f);
#pragma unroll
    for (int l = 0; l < 8; ++l) va[l] = (float)s8[l] * sc;
  } else {
    float bR[8];
#pragma unroll
    for (int l = 0; l < 8; ++l) bR[l] = 0.f;
#pragma unroll
    for (int i = 0; i < 8; ++i) {
      half8 s8 = *(const half8*)&Sw[i * 584 + rb];
#pragma unroll
      for (int l = 0; l < 8; ++l) bR[l] += p[i] * (float)s8[l];
    }
    const float rc = 1.f / (cR + 1e-6f);
#pragma unroll
    for (int l = 0; l < 8; ++l) va[l] = bR[l] * rc;
  }
  float mx = va[0];
#pragma unroll
  for (int l = 1; l < 8; ++l) mx = fmaxf(mx, va[l]);
  float ex[8], sm = 0.f;
#pragma unroll
  for (int l = 0; l < 8; ++l) { ex[l] = __expf(va[l] - mx); sm += ex[l]; }
  const float inv = 1.f / sm;
  float rr[8], rl = 0.f;
#pragma unroll
  for (int l = 0; l < 8; ++l) {
    rr[l] = ex[l] * inv;
    rl += rr[l] * __logf(fmaxf(rr[l], 1e-30f));
  }
  if (iter) {
    half8 r8;
#pragma unroll
    for (int l = 0; l < 8; ++l) r8[l] = (f16)rr[l];
    *(half8*)&Rg[sbase + kr * 64 + jr * 8] = r8;
  }
  // bL[i] = sum_l rr*S[i] - rl ; rows re-read from LDS (prefetchable)
  half8 blh;
#pragma unroll
  for (int i = 0; i < 8; ++i) {
    half8 s8 = *(const half8*)&Sw[i * 584 + rb];
    float s = 0.f;
#pragma unroll
    for (int l = 0; l < 8; ++l) s += rr[l] * (float)s8[l];
    blh[i] = (f16)(s - rl);
  }
  *(half8*)&Lp[lane * 8] = blh;
}

// ---------------- K5: joint softmax -> f16 probs Pg (permuted layout) -------
__global__ __launch_bounds__(256) void k_probs(
    const f16* __restrict__ Lg, f16* __restrict__ Pg) {
  __shared__ f16 Ls[32 * 584];   // 37,376 B ; layout f*584 + j*72 + k*8 + i
  __shared__ float stt[128];     // [j*8+i]{mx, 1/sum}
  const int t = threadIdx.x;
  const int g = 31 - (blockIdx.x & 31), bh = blockIdx.x >> 5;
  const int64_t sb = ((int64_t)bh * 528 + ((g * (g + 1)) >> 1)) * 512;
  const f16* Lp = Lg + sb;
  for (int f = 0; f <= g; ++f) {
    const int o = 2 * t;
    *(uint32_t*)&Ls[f * 584 + (o >> 6) * 72 + (o & 63)] =
        *(const uint32_t*)&Lp[f * 512 + o];
  }
  __syncthreads();
  {
    const int p = t >> 2, sub = t & 3;
    const int base = (p >> 3) * 72 + (p & 7);
    float mx = -1e30f;
    for (int f = sub; f <= g; f += 4)
#pragma unroll
      for (int k_ = 0; k_ < 8; ++k_)
        mx = fmaxf(mx, (float)Ls[f * 584 + base + k_ * 8]);
    mx = fmaxf(mx, __shfl_xor(mx, 1, 64));
    mx = fmaxf(mx, __shfl_xor(mx, 2, 64));
    float se = 0.f;
    for (int f = sub; f <= g; f += 4)
#pragma unroll
      for (int k_ = 0; k_ < 8; ++k_)
        se += __expf((float)Ls[f * 584 + base + k_ * 8] - mx);
    se += __shfl_xor(se, 1, 64);
    se += __shfl_xor(se, 2, 64);
    if (sub == 0) { stt[p * 2] = mx; stt[p * 2 + 1] = 1.f / se; }
  }
  __syncthreads();
  {
    const int r = t & 63, fq = t >> 6;
    const int j = r >> 3, k_ = r & 7;
    float mx[8], inv[8];
#pragma unroll
    for (int i = 0; i < 8; ++i) {
      mx[i] = stt[(j * 8 + i) * 2];
      inv[i] = stt[(j * 8 + i) * 2 + 1];
    }
    for (int fb = fq; fb <= g; fb += 4) {
      half8 row8 = *(const half8*)&Ls[fb * 584 + j * 72 + k_ * 8];
      float pr[8];
#pragma unroll
      for (int i = 0; i < 8; ++i) pr[i] = __expf((float)row8[i] - mx[i]) * inv[i];
      half8 st8;
      st8[0] = (f16)pr[0]; st8[1] = (f16)pr[2]; st8[2] = (f16)pr[4]; st8[3] = (f16)pr[6];
      st8[4] = (f16)pr[1]; st8[5] = (f16)pr[3]; st8[6] = (f16)pr[5]; st8[7] = (f16)pr[7];
      *(half8*)&Pg[sb + (int64_t)fb * 512 + r * 8] = st8;
    }
  }
}

// ---------------- K6: output — g-paired, f16 probs, 6 loads/iter, no exp ----
__global__ __launch_bounds__(512) void k_out(
    const f16* __restrict__ Pg, const f16* __restrict__ Rg,
    const f16* __restrict__ vth, float* __restrict__ out) {
  __shared__ float red[64 * 64];   // 16 KB
  const int t = threadIdx.x;
  const int wave = t >> 6, lane = t & 63, quad = lane >> 4, ln = lane & 15;
  const int fg = wave >> 2, dw = wave & 3;
  const int bh = blockIdx.x >> 4, G = blockIdx.x & 15;
  const int jl = ln & 7, ih = ln >> 3;
  const f16* vb = vth + ((int64_t)bh * 32 * 64 + dw * 16 + ln) * 64;

#pragma unroll 1
  for (int ph = 0; ph < 2; ++ph) {
    const int g = ph ? G : 31 - G;
    const int64_t sbase = ((int64_t)bh * 528 + ((g * (g + 1)) >> 1)) * 512;
    const f16* Pp = Pg + sbase;
    const f16* Rp = Rg + sbase;
    f32x4 oacc[4];
#pragma unroll
    for (int mt = 0; mt < 4; ++mt) { f32x4 z = {0.f, 0.f, 0.f, 0.f}; oacc[mt] = z; }

    half8 vA0, vA1, rA0, rA1; half4v pA0, pA1;
    half8 vB0, vB1, rB0, rB1; half4v pB0, pB1;
    auto loadit = [&](int f, half8& v0, half8& v1, half8& r0, half8& r1,
                      half4v& p0, half4v& p1) {
      const f16* Pf = Pp + f * 512;
      const f16* Rf = Rp + f * 512;
      const f16* vf = vb + (int64_t)f * 64 * 64;
      v0 = *(const half8*)&vf[quad * 8];
      v1 = *(const half8*)&vf[32 + quad * 8];
      r0 = *(const half8*)&Rf[quad * 64 + jl * 8];
      r1 = *(const half8*)&Rf[(4 + quad) * 64 + jl * 8];
      p0 = *(const half4v*)&Pf[jl * 64 + quad * 8 + ih * 4];
      p1 = *(const half4v*)&Pf[jl * 64 + (4 + quad) * 8 + ih * 4];
    };
    auto compit = [&](half8& v0, half8& v1, half8& r0, half8& r1,
                      half4v& p0, half4v& p1) {
#pragma unroll
      for (int mt = 0; mt < 4; ++mt) {
        const f16 Lh0 = p0[mt], Lh1 = p1[mt];
        half8 w0, w1;
#pragma unroll
        for (int l = 0; l < 8; ++l) { w0[l] = r0[l] * Lh0; w1[l] = r1[l] * Lh1; }
        oacc[mt] = mfma16(w0, v0, oacc[mt]);
        oacc[mt] = mfma16(w1, v1, oacc[mt]);
      }
    };
    int f = fg;
    if (f <= g) {
      loadit(f, vA0, vA1, rA0, rA1, pA0, pA1);
      while (true) {
        if (f + 2 <= g) {
          loadit(f + 2, vB0, vB1, rB0, rB1, pB0, pB1);
          compit(vA0, vA1, rA0, rA1, pA0, pA1);
          f += 2;
        } else { compit(vA0, vA1, rA0, rA1, pA0, pA1); break; }
        if (f + 2 <= g) {
          loadit(f + 2, vA0, vA1, rA0, rA1, pA0, pA1);
          compit(vB0, vB1, rB0, rB1, pB0, pB1);
          f += 2;
        } else { compit(vB0, vB1, rB0, rB1, pB0, pB1); break; }
      }
    }
    __syncthreads();
    if (fg == 1) {
#pragma unroll
      for (int mt = 0; mt < 4; ++mt)
#pragma unroll
        for (int r2 = 0; r2 < 4; ++r2)
          red[(dw * 16 + mt * 4 + r2) * 64 + lane] = oacc[mt][r2];
    }
    __syncthreads();
    if (fg == 0) {
#pragma unroll
      for (int mt = 0; mt < 4; ++mt)
#pragma unroll
        for (int r2 = 0; r2 < 4; ++r2)
          oacc[mt][r2] += red[(dw * 16 + mt * 4 + r2) * 64 + lane];
      float* ob = out + (int64_t)((bh >> 4) * 2048 + g * 64) * 1024 + (bh & 15) * 64;
#pragma unroll
      for (int mt = 0; mt < 4; ++mt)
#pragma unroll
        for (int r2 = 0; r2 < 4; ++r2)
          ob[(int64_t)(mt * 16 + quad * 4 + r2) * 1024 + dw * 16 + ln] = oacc[mt][r2];
    }
  }
}

// ---------------------------------------------------------------------------
extern "C" void kernel_launch(void* const* d_in, const int* in_sizes, int n_in,
                              void* d_out, int out_size, void* d_ws, size_t ws_size,
                              hipStream_t stream) {
  const float* x    = (const float*)d_in[0];
  const float* cosg = (const float*)d_in[1];
  const float* sing = (const float*)d_in[2];
  const float* wq   = (const float*)d_in[3];
  const float* wk   = (const float*)d_in[4];
  const float* wv   = (const float*)d_in[5];
  const float* gq   = (const float*)d_in[6];
  const float* gk   = (const float*)d_in[7];
  float* out = (float*)d_out;

  char* ws = (char*)d_ws;
  f16*   xh   = (f16*)(ws);                     // 8,388,608 B
  f16*   wcat = (f16*)(ws + 8388608);           // 6,291,456 B
  float* P    = (float*)(ws + 14680064);        // 50,331,648 B (dead after K3)
  f16*   Rg   = (f16*)(ws + 14680064);          // 17,301,504 B (aliases P)
  f16*   Pg   = (f16*)(ws + 31981568);          // 17,301,504 B (aliases P)
  f16*   qh   = (f16*)(ws + 65011712);          // 8,388,608 B
  f16*   kh   = (f16*)(ws + 73400320);          // 8,388,608 B
  f16*   vth  = (f16*)(ws + 81788928);          // 8,388,608 B
  f16*   Lg   = (f16*)(ws + 90177536);          // 17,301,504 B -> end ~108 MB

  hipLaunchKernelGGL(k_cast, dim3(1024), dim3(256), 0, stream, x, wq, wk, wv, xh, wcat);
  hipLaunchKernelGGL(k_gemm, dim3(768), dim3(256), 0, stream, xh, wcat, P);
  hipLaunchKernelGGL(k_epilogue, dim3(1024), dim3(256), 0, stream,
                     P, cosg, sing, gq, gk, qh, kh, vth);
  hipLaunchKernelGGL(k_phase, dim3(16896), dim3(64), 0, stream, qh, kh, Lg, Rg, Pg, 0);
  hipLaunchKernelGGL(k_probs, dim3(1024), dim3(256), 0, stream, Lg, Pg);
  hipLaunchKernelGGL(k_phase, dim3(16896), dim3(64), 0, stream, qh, kh, Lg, Rg, Pg, 1);
  hipLaunchKernelGGL(k_probs, dim3(1024), dim3(256), 0, stream, Lg, Pg);
  hipLaunchKernelGGL(k_out, dim3(512), dim3(512), 0, stream, Pg, Rg, vth, out);
}